// Round 16
// baseline (394.332 us; speedup 1.0000x reference)
//
#include <hip/hip_runtime.h>
#include <hip/hip_bf16.h>
#include <stdint.h>

typedef __hip_bfloat16 bf16;
typedef __attribute__((ext_vector_type(8))) short short8;
typedef __attribute__((ext_vector_type(4))) float floatx4;

#define D_MODEL 1024
#define D_STATE 16
#define D_INNER 2048
#define DT_RANK 64
#define BB 2
#define LL 2048
#define BL (BB * LL)            // 4096 rows
#define XZ_LD (2 * D_INNER)     // 4096 (fallback path only)
#define DBL_LD (DT_RANK + 2 * D_STATE)  // 96
#define NCH 64                  // time chunks for parallel scan
#define TCH (LL / NCH)          // 32 steps per chunk

__device__ __forceinline__ bf16 f2b(float f) { return __float2bfloat16(f); }

// fast sigmoid / softplus via native v_exp/v_log/v_rcp (~3e-7 rel err)
__device__ __forceinline__ float fsig(float v)  { return __fdividef(1.f, 1.f + __expf(-v)); }
__device__ __forceinline__ float fsoftp(float v){ return fmaxf(v, 0.f) + __logf(1.f + __expf(-fabsf(v))); }

// async 16B global -> LDS (wave-uniform LDS base + lane*16; rows contiguous)
__device__ __forceinline__ void gload16(const void* g, void* l) {
    __builtin_amdgcn_global_load_lds(
        (const __attribute__((address_space(1))) uint32_t*)(uintptr_t)g,
        (__attribute__((address_space(3))) uint32_t*)(uintptr_t)l,
        16, 0, 0);
}

#define S0 (4096 * 1024)   // W_in
#define S1 (128 * 2048)    // W_xproj padded to 128 rows
#define S2 (2048 * 64)     // W_dt
#define S3 (1024 * 2048)   // W_out
#define S4 (BL * DBL_LD)   // dbl zero-init (for split-K atomics)
#define WCVT_TOT (S0 + S1 + S2 + S3 + S4)

// --------- weight conversion (+pad W_xproj, +zero dbl) — runs FIRST ---------
// so its dirty L2 lines drain during ln_kernel, not during G2 (R15 fused this
// with LN and G2 regressed 78->99 us; R12's separated order had G2 at 78).
__global__ __launch_bounds__(256) void wcvt_kernel(
    const float* __restrict__ Win, const float* __restrict__ Wx,
    const float* __restrict__ Wdt, const float* __restrict__ Wout,
    bf16* __restrict__ win_bf, bf16* __restrict__ wx_bf,
    bf16* __restrict__ wdt_bf, bf16* __restrict__ wout_bf,
    float* __restrict__ dbl)
{
    int id = blockIdx.x * 256 + threadIdx.x;
    if (id < S0) { win_bf[id] = f2b(Win[id]); return; }
    id -= S0;
    if (id < S1) { wx_bf[id] = (id < 96 * 2048) ? f2b(Wx[id]) : f2b(0.f); return; }
    id -= S1;
    if (id < S2) { wdt_bf[id] = f2b(Wdt[id]); return; }
    id -= S2;
    if (id < S3) { wout_bf[id] = f2b(Wout[id]); return; }
    id -= S3;
    dbl[id] = 0.f;
}

// ---------------- LayerNorm: one block per row; bf16 out ---------------------
__global__ __launch_bounds__(256) void ln_kernel_bf(
    const float* __restrict__ x, const float* __restrict__ w,
    const float* __restrict__ b, bf16* __restrict__ xnb)
{
    __shared__ float s1[256], s2[256];
    const int row = blockIdx.x;
    const int tid = threadIdx.x;
    const float* xr = x + (size_t)row * D_MODEL;
    float v[4], sum = 0.f, sq = 0.f;
#pragma unroll
    for (int i = 0; i < 4; ++i) {
        v[i] = xr[tid + 256 * i];
        sum += v[i];
        sq  += v[i] * v[i];
    }
    s1[tid] = sum; s2[tid] = sq;
    __syncthreads();
    for (int s = 128; s > 0; s >>= 1) {
        if (tid < s) { s1[tid] += s1[tid + s]; s2[tid] += s2[tid + s]; }
        __syncthreads();
    }
    const float mu  = s1[0] * (1.f / D_MODEL);
    const float var = s2[0] * (1.f / D_MODEL) - mu * mu;
    const float rs  = rsqrtf(var + 1e-5f);
#pragma unroll
    for (int i = 0; i < 4; ++i) {
        const int c = tid + 256 * i;
        xnb[(size_t)row * D_MODEL + c] = f2b((v[i] - mu) * rs * w[c] + b[c]);
    }
}

// ------------- final reduce: out = x + p0 + p1 (float4) ----------------------
__global__ __launch_bounds__(256) void reduce_out(
    const float* __restrict__ x, const float* __restrict__ p0,
    const float* __restrict__ p1, float* __restrict__ out)
{
    const int id = blockIdx.x * 256 + threadIdx.x;
    const float4 a = ((const float4*)x)[id];
    const float4 u = ((const float4*)p0)[id];
    const float4 v = ((const float4*)p1)[id];
    float4 r;
    r.x = a.x + u.x + v.x; r.y = a.y + u.y + v.y;
    r.z = a.z + u.z + v.z; r.w = a.w + u.w + v.w;
    ((float4*)out)[id] = r;
}

// ============ bf16 MFMA GEMM (R9-proven, BK=32): C = A[M,K] * B[N,K]^T =======
// epi: 0=plain fp32 store to slab C + blockIdx.z*BL*D_MODEL (G7 split-K slabs);
//      1=+bias softplus (fp32 C); 3=atomicAdd (split-K); 4=u/z split
//      (gn<D_INNER -> fp32 C, else bf16 C2); 5=+bias softplus bf16 to C2
#define GTM 128
#define GTN 128
#define GTK 32

__global__ __launch_bounds__(256) void gemm_bf(
    const bf16* __restrict__ A, int lda,
    const bf16* __restrict__ B, int ldb,
    float* __restrict__ C, int ldc,
    int N, int K, int epi,
    const float* __restrict__ bias,
    bf16* __restrict__ C2)
{
    __shared__ short As[GTM * GTK];   // 8 KB
    __shared__ short Bs[GTN * GTK];   // 8 KB
    const int tid  = threadIdx.x;
    const int lane = tid & 63;
    const int wave = tid >> 6;            // 0..3
    const int wm = (wave & 1) * 64;
    const int wn = (wave >> 1) * 64;
    const int bm = blockIdx.y * GTM;
    const int bn = blockIdx.x * GTN;
    const int kbase = blockIdx.z * K;     // split-K base (K = slice length)

    floatx4 acc[4][4];
#pragma unroll
    for (int i = 0; i < 4; ++i)
#pragma unroll
        for (int j = 0; j < 4; ++j) acc[i][j] = (floatx4){0.f, 0.f, 0.f, 0.f};

    const int srow = wave * 16 + (lane >> 2);   // 0..63 (per pass)
    const int scol = (lane & 3) * 8;            // bf16 col within k-tile
    const int fm = lane & 15;
    const int q  = lane >> 4;

    for (int k0 = 0; k0 < K; k0 += GTK) {
#pragma unroll
        for (int r = 0; r < 2; ++r) {
            const int m = r * 64 + srow;
            gload16(A + (size_t)(bm + m) * lda + kbase + k0 + scol,
                    As + m * GTK + scol);
            gload16(B + (size_t)(bn + m) * ldb + kbase + k0 + scol,
                    Bs + m * GTK + scol);
        }
        __syncthreads();

        short8 af[4], bfr[4];
#pragma unroll
        for (int i = 0; i < 4; ++i)
            af[i] = *(short8*)&As[(wm + i * 16 + fm) * GTK + q * 8];
#pragma unroll
        for (int j = 0; j < 4; ++j)
            bfr[j] = *(short8*)&Bs[(wn + j * 16 + fm) * GTK + q * 8];
#pragma unroll
        for (int i = 0; i < 4; ++i)
#pragma unroll
            for (int j = 0; j < 4; ++j)
                acc[i][j] = __builtin_amdgcn_mfma_f32_16x16x32_bf16(
                    af[i], bfr[j], acc[i][j], 0, 0, 0);
        __syncthreads();
    }

    // C/D layout: col=lane&15, row=(lane>>4)*4+reg  [m89/m91-verified]
    const int col = lane & 15;
    const int rq  = (lane >> 4) * 4;
#pragma unroll
    for (int i = 0; i < 4; ++i) {
#pragma unroll
        for (int j = 0; j < 4; ++j) {
#pragma unroll
            for (int r = 0; r < 4; ++r) {
                const int gm = bm + wm + i * 16 + rq + r;
                const int gn = bn + wn + j * 16 + col;
                if (gn >= N) continue;
                float v = acc[i][j][r];
                if (epi == 0) {
                    C[(size_t)blockIdx.z * BL * D_MODEL +
                      (size_t)gm * ldc + gn] = v;
                } else if (epi == 1) {
                    C[(size_t)gm * ldc + gn] = fsoftp(v + bias[gn]);
                } else if (epi == 3) {
                    atomicAdd(&C[(size_t)gm * ldc + gn], v);
                } else if (epi == 4) {
                    if (gn < D_INNER) C[(size_t)gm * ldc + gn] = v;
                    else C2[(size_t)gm * (size_t)D_INNER + (gn - D_INNER)] = f2b(v);
                } else {  // 5
                    C2[(size_t)gm * ldc + gn] = f2b(fsoftp(v + bias[gn]));
                }
            }
        }
    }
}

// ------------- conv(4)+SiLU: reads fp32 uraw, writes bf16 uc -----------------
__global__ __launch_bounds__(256) void conv_par3(
    const float* __restrict__ uraw, const float* __restrict__ cw,
    const float* __restrict__ cb, bf16* __restrict__ ucb)
{
    const int id = blockIdx.x * 256 + threadIdx.x;  // = (b*LL+t)*D_INNER+d
    const int d = id & (D_INNER - 1);
    const int t = (id >> 11) & (LL - 1);
    float acc = cb[d];
#pragma unroll
    for (int k = 0; k < 4; ++k) {
        const int tt = t - 3 + k;
        if (tt >= 0)
            acc += uraw[(size_t)id + (size_t)(k - 3) * D_INNER] * cw[d * 4 + k];
    }
    ucb[id] = f2b(acc * fsig(acc));
}

// ------------- dbl[:, :64] -> bf16 dt_r copy for GEMM-5 ----------------------
__global__ __launch_bounds__(256) void cvt_dtr(
    const float* __restrict__ dbl, bf16* __restrict__ dtr_bf)
{
    const int id = blockIdx.x * 256 + threadIdx.x;  // m*64+r
    const int m = id >> 6, r = id & 63;
    dtr_bf[id] = f2b(dbl[(size_t)m * DBL_LD + r]);
}

// ------------------------------ 3-phase scan ---------------------------------
// block decode: blk = ((b*NCH)+c)*8 + dgrp ; d = dgrp*256 + tid
__global__ __launch_bounds__(256) void scan_p1(
    const bf16* __restrict__ uc, const bf16* __restrict__ dtb,
    const float* __restrict__ dbl, const float* __restrict__ A_log,
    float* __restrict__ Psum, float* __restrict__ Hloc)
{
    const int blk = blockIdx.x;
    const int d = (blk & 7) * 256 + threadIdx.x;
    const int c = (blk >> 3) & (NCH - 1);
    const int b = blk >> 9;                  // NCH=64 -> 9 bits below b
    float A[D_STATE], h[D_STATE];
#pragma unroll
    for (int n = 0; n < D_STATE; ++n) {
        A[n] = -__expf(A_log[d * D_STATE + n]);
        h[n] = 0.f;
    }
    const size_t row0 = (size_t)b * LL + c * TCH;
    const bf16* dtp = dtb + row0 * D_INNER + d;
    const bf16* up  = uc  + row0 * D_INNER + d;
    const float* Bp = dbl + row0 * DBL_LD + DT_RANK;
    float S = 0.f;
    for (int t = 0; t < TCH; ++t) {
        const float dtv = (float)dtp[(size_t)t * D_INNER];
        const float uv  = (float)up[(size_t)t * D_INNER];
        const float du  = dtv * uv;
        S += dtv;
#pragma unroll
        for (int n = 0; n < D_STATE; ++n)
            h[n] = __expf(dtv * A[n]) * h[n] + du * Bp[(size_t)t * DBL_LD + n];
    }
    const size_t o = (((size_t)b * NCH + c) * D_INNER + d) * D_STATE;
#pragma unroll
    for (int n = 0; n < D_STATE; ++n) {
        Psum[o + n] = __expf(S * A[n]);
        Hloc[o + n] = h[n];
    }
}

__global__ __launch_bounds__(256) void scan_p2(
    float* __restrict__ Psum, const float* __restrict__ Hloc)
{
    const int id = blockIdx.x * 256 + threadIdx.x;
    const int dn = id & (D_INNER * D_STATE - 1);
    const int b  = id >> 15;
    float h = 0.f;
    for (int c = 0; c < NCH; ++c) {
        const size_t o = ((size_t)(b * NCH + c) * D_INNER * D_STATE) + dn;
        const float P  = Psum[o];
        const float hl = Hloc[o];
        Psum[o] = h;          // Hin for chunk c
        h = P * h + hl;
    }
}

// phase 3: replay; bf16 u (ucy), bf16 dt, bf16 z (zbf); y overwrites ucy
__global__ __launch_bounds__(256) void scan_p3b(
    bf16* __restrict__ ucy, const bf16* __restrict__ dtb,
    const float* __restrict__ dbl, const float* __restrict__ A_log,
    const float* __restrict__ Dw, const float* __restrict__ Hin,
    const bf16* __restrict__ zbf)
{
    const int blk = blockIdx.x;
    const int d = (blk & 7) * 256 + threadIdx.x;
    const int c = (blk >> 3) & (NCH - 1);
    const int b = blk >> 9;                  // NCH=64 -> 9 bits below b
    float A[D_STATE], h[D_STATE];
    const size_t o = (((size_t)b * NCH + c) * D_INNER + d) * D_STATE;
#pragma unroll
    for (int n = 0; n < D_STATE; ++n) {
        A[n] = -__expf(A_log[d * D_STATE + n]);
        h[n] = Hin[o + n];
    }
    const float Dd = Dw[d];
    const size_t row0 = (size_t)b * LL + c * TCH;
    const bf16* dtp = dtb + row0 * D_INNER + d;
    bf16*       uyp = ucy + row0 * D_INNER + d;     // u in, y out (same slot)
    const float* BCp = dbl + row0 * DBL_LD;
    const bf16* zp   = zbf + row0 * D_INNER + d;
    for (int t = 0; t < TCH; ++t) {
        const float dtv = (float)dtp[(size_t)t * D_INNER];
        const float uv  = (float)uyp[(size_t)t * D_INNER];
        const float du  = dtv * uv;
        float acc = uv * Dd;
        const float* Brow = BCp + (size_t)t * DBL_LD + DT_RANK;
        const float* Crow = Brow + D_STATE;
#pragma unroll
        for (int n = 0; n < D_STATE; ++n) {
            h[n] = __expf(dtv * A[n]) * h[n] + du * Brow[n];
            acc += h[n] * Crow[n];
        }
        const float zv = (float)zp[(size_t)t * D_INNER];
        uyp[(size_t)t * D_INNER] = f2b(acc * zv * fsig(zv));
    }
}

// ---------------- fallback (small ws): R4 sequential path --------------------
#define BM 128
#define BN 128
#define BK 8

__global__ __launch_bounds__(256) void ln_kernel(
    const float* __restrict__ x, const float* __restrict__ w,
    const float* __restrict__ b, float* __restrict__ xnf)
{
    __shared__ float s1[256], s2[256];
    const int row = blockIdx.x;
    const int tid = threadIdx.x;
    const float* xr = x + (size_t)row * D_MODEL;
    float v[4], sum = 0.f, sq = 0.f;
#pragma unroll
    for (int i = 0; i < 4; ++i) {
        v[i] = xr[tid + 256 * i];
        sum += v[i];
        sq  += v[i] * v[i];
    }
    s1[tid] = sum; s2[tid] = sq;
    __syncthreads();
    for (int s = 128; s > 0; s >>= 1) {
        if (tid < s) { s1[tid] += s1[tid + s]; s2[tid] += s2[tid + s]; }
        __syncthreads();
    }
    const float mu  = s1[0] * (1.f / D_MODEL);
    const float var = s2[0] * (1.f / D_MODEL) - mu * mu;
    const float rs  = rsqrtf(var + 1e-5f);
#pragma unroll
    for (int i = 0; i < 4; ++i) {
        const int c = tid + 256 * i;
        xnf[(size_t)row * D_MODEL + c] = (v[i] - mu) * rs * w[c] + b[c];
    }
}

__global__ __launch_bounds__(256) void gemm_bt(
    const float* __restrict__ A, int lda,
    const float* __restrict__ Bw,
    float* __restrict__ C, int ldc,
    int M, int N, int K, int epi,
    const float* __restrict__ bias,
    const float* __restrict__ resid)
{
    __shared__ float As[BK][BM + 1];
    __shared__ float Bs[BK][BN + 1];
    const int tx = threadIdx.x, ty = threadIdx.y;
    const int tid = ty * 16 + tx;
    const int bm = blockIdx.y * BM, bn = blockIdx.x * BN;
    float acc[8][8];
#pragma unroll
    for (int i = 0; i < 8; ++i)
#pragma unroll
        for (int j = 0; j < 8; ++j) acc[i][j] = 0.f;
    for (int k0 = 0; k0 < K; k0 += BK) {
#pragma unroll
        for (int i = tid; i < BM * BK; i += 256) {
            const int m = i / BK, kk = i % BK;
            As[kk][m] = A[(size_t)(bm + m) * lda + (k0 + kk)];
        }
#pragma unroll
        for (int i = tid; i < BN * BK; i += 256) {
            const int n = i / BK, kk = i % BK;
            const int gn = bn + n;
            Bs[kk][n] = (gn < N) ? Bw[(size_t)gn * K + (k0 + kk)] : 0.f;
        }
        __syncthreads();
#pragma unroll
        for (int kk = 0; kk < BK; ++kk) {
            float av[8], bv[8];
#pragma unroll
            for (int i = 0; i < 8; ++i) av[i] = As[kk][ty * 8 + i];
#pragma unroll
            for (int j = 0; j < 8; ++j) bv[j] = Bs[kk][tx * 8 + j];
#pragma unroll
            for (int i = 0; i < 8; ++i)
#pragma unroll
                for (int j = 0; j < 8; ++j) acc[i][j] += av[i] * bv[j];
        }
        __syncthreads();
    }
#pragma unroll
    for (int i = 0; i < 8; ++i) {
        const int gm = bm + ty * 8 + i;
#pragma unroll
        for (int j = 0; j < 8; ++j) {
            const int gn = bn + tx * 8 + j;
            if (gn >= N) continue;
            float v = acc[i][j];
            if (epi == 1) {
                v += bias[gn];
                v = fmaxf(v, 0.f) + log1pf(expf(-fabsf(v)));
            } else if (epi == 2) {
                v += resid[(size_t)gm * ldc + gn];
            }
            C[(size_t)gm * ldc + gn] = v;
        }
    }
}

__global__ __launch_bounds__(256) void conv_silu_kernel(
    float* __restrict__ xz, const float* __restrict__ cw,
    const float* __restrict__ cb)
{
    const int idx = blockIdx.x * 256 + threadIdx.x;
    const int b = idx >> 11, d = idx & (D_INNER - 1);
    const float w0 = cw[d * 4 + 0], w1 = cw[d * 4 + 1];
    const float w2 = cw[d * 4 + 2], w3 = cw[d * 4 + 3];
    const float bias = cb[d];
    float* u = xz + (size_t)b * LL * XZ_LD + d;
    float x0 = 0.f, x1 = 0.f, x2 = 0.f;
    for (int t = 0; t < LL; ++t) {
        const float x3 = u[(size_t)t * XZ_LD];
        const float c = bias + x0 * w0 + x1 * w1 + x2 * w2 + x3 * w3;
        u[(size_t)t * XZ_LD] = c / (1.f + expf(-c));
        x0 = x1; x1 = x2; x2 = x3;
    }
}

__global__ __launch_bounds__(256) void scan_kernel(
    float* __restrict__ xz, const float* __restrict__ dtb,
    const float* __restrict__ dbl,
    const float* __restrict__ A_log, const float* __restrict__ Dw)
{
    const int idx = blockIdx.x * 256 + threadIdx.x;
    const int b = idx >> 11, d = idx & (D_INNER - 1);
    float A[D_STATE], h[D_STATE];
#pragma unroll
    for (int n = 0; n < D_STATE; ++n) {
        A[n] = -expf(A_log[d * D_STATE + n]);
        h[n] = 0.f;
    }
    const float Dd = Dw[d];
    const float* dtp  = dtb + (size_t)b * LL * D_INNER + d;
    float*       up   = xz  + (size_t)b * LL * XZ_LD + d;
    const float* dblp = dbl + (size_t)b * LL * DBL_LD;
    for (int t = 0; t < LL; ++t) {
        const float dtv = dtp[(size_t)t * D_INNER];
        const float uv  = up[(size_t)t * XZ_LD];
        const float zv  = up[(size_t)t * XZ_LD + D_INNER];
        const float* Brow = dblp + (size_t)t * DBL_LD + DT_RANK;
        const float* Crow = Brow + D_STATE;
        const float du = dtv * uv;
        float acc = uv * Dd;
#pragma unroll
        for (int n = 0; n < D_STATE; ++n) {
            const float dA = expf(dtv * A[n]);
            h[n] = dA * h[n] + du * Brow[n];
            acc += h[n] * Crow[n];
        }
        const float sz = zv / (1.f + expf(-zv));
        up[(size_t)t * XZ_LD] = acc * sz;
    }
}

extern "C" void kernel_launch(void* const* d_in, const int* in_sizes, int n_in,
                              void* d_out, int out_size, void* d_ws, size_t ws_size,
                              hipStream_t stream)
{
    const float* x       = (const float*)d_in[0];
    const float* ln_w    = (const float*)d_in[1];
    const float* ln_b    = (const float*)d_in[2];
    const float* W_in    = (const float*)d_in[3];
    const float* conv_w  = (const float*)d_in[4];
    const float* conv_b  = (const float*)d_in[5];
    const float* W_xproj = (const float*)d_in[6];
    const float* W_dt    = (const float*)d_in[7];
    const float* b_dt    = (const float*)d_in[8];
    const float* A_log   = (const float*)d_in[9];
    const float* Dw      = (const float*)d_in[10];
    const float* W_out   = (const float*)d_in[11];
    float* out = (float*)d_out;

    // ws layout identical to R15 (134.8 MiB, each size audited):
    //   dtb_bf [0,        4194304)   bf16 dt 4096x2048
    //   uraw   [4194304, 12582912)   fp32 u  4096x2048
    //   zbf    [12582912, 16777216)  bf16 z  4096x2048
    //   Psum   [16777216, 20971520)  fp32; later G7 slab 0
    //   Hloc   [20971520, 25165824)  fp32; later G7 slab 1
    //   dbl    [25165824, 25559040)  fp32 4096x96
    //   ucy    [25559040, 29753344)  bf16 conv(u) then y
    //   xn_bf  [29753344, 31850496)  bf16 4096x1024
    //   win_bf [31850496, 33947648)  bf16 4096x1024
    //   wx_bf  [33947648, 34078720) | wdt_bf [34078720, 34144256)
    //   wout_bf[34144256, 35192832) | dtr_bf [35192832, 35323904)
    float* wsf     = (float*)d_ws;
    bf16*  dtb_bf  = (bf16*)wsf;
    float* uraw    = wsf + 4194304;
    bf16*  zbf     = (bf16*)(wsf + 12582912);
    float* Psum    = wsf + 16777216;       // G7 slabs are contiguous here
    float* Hloc    = wsf + 20971520;
    float* dbl     = wsf + 25165824;
    bf16*  ucy     = (bf16*)(wsf + 25559040);
    bf16*  xn_bf   = (bf16*)(wsf + 29753344);
    bf16*  win_bf  = (bf16*)(wsf + 31850496);
    bf16*  wx_bf   = (bf16*)(wsf + 33947648);
    bf16*  wdt_bf  = (bf16*)(wsf + 34078720);
    bf16*  wout_bf = (bf16*)(wsf + 34144256);
    bf16*  dtr_bf  = (bf16*)(wsf + 35192832);
    const size_t need_big = (size_t)35323904 * sizeof(float);

    if (ws_size >= need_big) {
        // wcvt FIRST, then LN — the ~10 us of LN lets wcvt's 14 MB of dirty
        // weight writes drain before G2 (R12-proven order; R15's fusion
        // regressed G2 78->99 us).
        wcvt_kernel<<<WCVT_TOT / 256, 256, 0, stream>>>(
            W_in, W_xproj, W_dt, W_out, win_bf, wx_bf, wdt_bf, wout_bf, dbl);
        ln_kernel_bf<<<BL, 256, 0, stream>>>(x, ln_w, ln_b, xn_bf);
        // G2: [u|z] = xn @ W_in^T; u -> fp32 uraw, z -> bf16 zbf
        gemm_bf<<<dim3(XZ_LD / GTN, BL / GTM, 1), 256, 0, stream>>>(
            xn_bf, D_MODEL, win_bf, D_MODEL, uraw, D_INNER,
            XZ_LD, D_MODEL, 4, nullptr, zbf);
        // conv+SiLU: fp32 u -> bf16 uc
        conv_par3<<<(size_t)BL * D_INNER / 256, 256, 0, stream>>>(
            uraw, conv_w, conv_b, ucy);
        // G4: dbl += uc @ W_xproj^T  (N=96 pad 128, split-K=8, atomic)
        gemm_bf<<<dim3(1, BL / GTM, 8), 256, 0, stream>>>(
            ucy, D_INNER, wx_bf, D_INNER, dbl, DBL_LD,
            DBL_LD, D_INNER / 8, 3, nullptr, nullptr);
        cvt_dtr<<<BL * DT_RANK / 256, 256, 0, stream>>>(dbl, dtr_bf);
        // G5: dt = softplus(dt_r @ W_dt^T + b_dt), bf16 store
        gemm_bf<<<dim3(D_INNER / GTN, BL / GTM, 1), 256, 0, stream>>>(
            dtr_bf, DT_RANK, wdt_bf, DT_RANK, nullptr, D_INNER,
            D_INNER, DT_RANK, 5, b_dt, dtb_bf);
        // chunked scan, NCH=64
        scan_p1<<<BB * NCH * 8, 256, 0, stream>>>(
            ucy, dtb_bf, dbl, A_log, Psum, Hloc);
        scan_p2<<<BB * D_INNER * D_STATE / 256, 256, 0, stream>>>(Psum, Hloc);
        scan_p3b<<<BB * NCH * 8, 256, 0, stream>>>(
            ucy, dtb_bf, dbl, A_log, Dw, Psum, zbf);
        // G7: partials = y @ W_out^T  (split-K=2 into Psum/Hloc slabs, plain
        // fp32 stores — no atomics)
        gemm_bf<<<dim3(D_MODEL / GTN, BL / GTM, 2), 256, 0, stream>>>(
            ucy, D_INNER, wout_bf, D_INNER, Psum, D_MODEL,
            D_MODEL, D_INNER / 2, 0, nullptr, nullptr);
        // out = x + p0 + p1
        reduce_out<<<BL * D_MODEL / 4 / 256, 256, 0, stream>>>(
            x, Psum, Hloc, out);
    } else {
        float* fdtb = wsf;
        float* fxn  = fdtb;
        float* fxz  = fdtb + (size_t)BL * D_INNER;
        float* fdbl = fxz + (size_t)BL * XZ_LD;
        ln_kernel<<<BL, 256, 0, stream>>>(x, ln_w, ln_b, fxn);
        dim3 blk(16, 16);
        gemm_bt<<<dim3(XZ_LD / BN, BL / BM), blk, 0, stream>>>(
            fxn, D_MODEL, W_in, fxz, XZ_LD, BL, XZ_LD, D_MODEL, 0, nullptr, nullptr);
        conv_silu_kernel<<<(BB * D_INNER) / 256, 256, 0, stream>>>(fxz, conv_w, conv_b);
        gemm_bt<<<dim3(1, BL / BM), blk, 0, stream>>>(
            fxz, XZ_LD, W_xproj, fdbl, DBL_LD, BL, DBL_LD, D_INNER, 0, nullptr, nullptr);
        gemm_bt<<<dim3(D_INNER / BN, BL / BM), blk, 0, stream>>>(
            fdbl, DBL_LD, W_dt, fdtb, D_INNER, BL, D_INNER, DT_RANK, 1, b_dt, nullptr);
        scan_kernel<<<(BB * D_INNER) / 256, 256, 0, stream>>>(fxz, fdtb, fdbl, A_log, Dw);
        gemm_bt<<<dim3(D_MODEL / BN, BL / BM), blk, 0, stream>>>(
            fxz, XZ_LD, W_out, out, D_MODEL, BL, D_MODEL, D_INNER, 2, nullptr, x);
    }
}

// Round 17
// 370.621 us; speedup vs baseline: 1.0640x; 1.0640x over previous
//
#include <hip/hip_runtime.h>
#include <hip/hip_bf16.h>
#include <stdint.h>

typedef __hip_bfloat16 bf16;
typedef __attribute__((ext_vector_type(8))) short short8;
typedef __attribute__((ext_vector_type(4))) float floatx4;

#define D_MODEL 1024
#define D_STATE 16
#define D_INNER 2048
#define DT_RANK 64
#define BB 2
#define LL 2048
#define BL (BB * LL)            // 4096 rows
#define XZ_LD (2 * D_INNER)     // 4096 (fallback path only)
#define DBL_LD (DT_RANK + 2 * D_STATE)  // 96
#define NCH 64                  // time chunks for parallel scan
#define TCH (LL / NCH)          // 32 steps per chunk

__device__ __forceinline__ bf16 f2b(float f) { return __float2bfloat16(f); }

// fast sigmoid / softplus via native v_exp/v_log/v_rcp (~3e-7 rel err)
__device__ __forceinline__ float fsig(float v)  { return __fdividef(1.f, 1.f + __expf(-v)); }
__device__ __forceinline__ float fsoftp(float v){ return fmaxf(v, 0.f) + __logf(1.f + __expf(-fabsf(v))); }

// async 16B global -> LDS (wave-uniform LDS base + lane*16; rows contiguous)
__device__ __forceinline__ void gload16(const void* g, void* l) {
    __builtin_amdgcn_global_load_lds(
        (const __attribute__((address_space(1))) uint32_t*)(uintptr_t)g,
        (__attribute__((address_space(3))) uint32_t*)(uintptr_t)l,
        16, 0, 0);
}

#define S0 (4096 * 1024)   // W_in
#define S1 (128 * 2048)    // W_xproj padded to 128 rows
#define S2 (2048 * 64)     // W_dt
#define S3 (1024 * 2048)   // W_out
#define S4 (BL * DBL_LD)   // dbl zero-init (for split-K atomics)
#define WCVT_TOT (S0 + S1 + S2 + S3 + S4)

// --------- weight conversion (+pad W_xproj, +zero dbl) — runs FIRST ---------
__global__ __launch_bounds__(256) void wcvt_kernel(
    const float* __restrict__ Win, const float* __restrict__ Wx,
    const float* __restrict__ Wdt, const float* __restrict__ Wout,
    bf16* __restrict__ win_bf, bf16* __restrict__ wx_bf,
    bf16* __restrict__ wdt_bf, bf16* __restrict__ wout_bf,
    float* __restrict__ dbl)
{
    int id = blockIdx.x * 256 + threadIdx.x;
    if (id < S0) { win_bf[id] = f2b(Win[id]); return; }
    id -= S0;
    if (id < S1) { wx_bf[id] = (id < 96 * 2048) ? f2b(Wx[id]) : f2b(0.f); return; }
    id -= S1;
    if (id < S2) { wdt_bf[id] = f2b(Wdt[id]); return; }
    id -= S2;
    if (id < S3) { wout_bf[id] = f2b(Wout[id]); return; }
    id -= S3;
    dbl[id] = 0.f;
}

// ---------------- LayerNorm: one block per row; bf16 out ---------------------
__global__ __launch_bounds__(256) void ln_kernel_bf(
    const float* __restrict__ x, const float* __restrict__ w,
    const float* __restrict__ b, bf16* __restrict__ xnb)
{
    __shared__ float s1[256], s2[256];
    const int row = blockIdx.x;
    const int tid = threadIdx.x;
    const float* xr = x + (size_t)row * D_MODEL;
    float v[4], sum = 0.f, sq = 0.f;
#pragma unroll
    for (int i = 0; i < 4; ++i) {
        v[i] = xr[tid + 256 * i];
        sum += v[i];
        sq  += v[i] * v[i];
    }
    s1[tid] = sum; s2[tid] = sq;
    __syncthreads();
    for (int s = 128; s > 0; s >>= 1) {
        if (tid < s) { s1[tid] += s1[tid + s]; s2[tid] += s2[tid + s]; }
        __syncthreads();
    }
    const float mu  = s1[0] * (1.f / D_MODEL);
    const float var = s2[0] * (1.f / D_MODEL) - mu * mu;
    const float rs  = rsqrtf(var + 1e-5f);
#pragma unroll
    for (int i = 0; i < 4; ++i) {
        const int c = tid + 256 * i;
        xnb[(size_t)row * D_MODEL + c] = f2b((v[i] - mu) * rs * w[c] + b[c]);
    }
}

// ------------- final reduce: out = x + p0 + p1 (float4) ----------------------
__global__ __launch_bounds__(256) void reduce_out(
    const float* __restrict__ x, const float* __restrict__ p0,
    const float* __restrict__ p1, float* __restrict__ out)
{
    const int id = blockIdx.x * 256 + threadIdx.x;
    const float4 a = ((const float4*)x)[id];
    const float4 u = ((const float4*)p0)[id];
    const float4 v = ((const float4*)p1)[id];
    float4 r;
    r.x = a.x + u.x + v.x; r.y = a.y + u.y + v.y;
    r.z = a.z + u.z + v.z; r.w = a.w + u.w + v.w;
    ((float4*)out)[id] = r;
}

// ===== bf16 MFMA GEMM, compile-time-specialized epilogues ====================
// R16 post-mortem: one mega-kernel with 5 runtime epi branches ran G2 at 99 us
// (VGPR 76); R12's 4-branch version ran it at 78 (VGPR 72). Specializing per
// call site eliminates dead branches and lets each instantiation get minimal
// registers.  EPI: 0=slab fp32 store (+blockIdx.z*BL*D_MODEL); 3=atomicAdd;
// 4=u/z split (gn<D_INNER -> fp32 C else bf16 C2); 5=softplus bf16 -> C2.
#define GTM 128
#define GTN 128
#define GTK 32

template <int EPI>
__global__ __launch_bounds__(256) void gemm_t(
    const bf16* __restrict__ A, int lda,
    const bf16* __restrict__ B, int ldb,
    float* __restrict__ C, int ldc,
    int N, int K,
    const float* __restrict__ bias,
    bf16* __restrict__ C2)
{
    __shared__ short As[GTM * GTK];   // 8 KB
    __shared__ short Bs[GTN * GTK];   // 8 KB
    const int tid  = threadIdx.x;
    const int lane = tid & 63;
    const int wave = tid >> 6;            // 0..3
    const int wm = (wave & 1) * 64;
    const int wn = (wave >> 1) * 64;
    const int bm = blockIdx.y * GTM;
    const int bn = blockIdx.x * GTN;
    const int kbase = blockIdx.z * K;     // split-K base (K = slice length)

    floatx4 acc[4][4];
#pragma unroll
    for (int i = 0; i < 4; ++i)
#pragma unroll
        for (int j = 0; j < 4; ++j) acc[i][j] = (floatx4){0.f, 0.f, 0.f, 0.f};

    const int srow = wave * 16 + (lane >> 2);   // 0..63 (per pass)
    const int scol = (lane & 3) * 8;            // bf16 col within k-tile
    const int fm = lane & 15;
    const int q  = lane >> 4;

    for (int k0 = 0; k0 < K; k0 += GTK) {
#pragma unroll
        for (int r = 0; r < 2; ++r) {
            const int m = r * 64 + srow;
            gload16(A + (size_t)(bm + m) * lda + kbase + k0 + scol,
                    As + m * GTK + scol);
            gload16(B + (size_t)(bn + m) * ldb + kbase + k0 + scol,
                    Bs + m * GTK + scol);
        }
        __syncthreads();

        short8 af[4], bfr[4];
#pragma unroll
        for (int i = 0; i < 4; ++i)
            af[i] = *(short8*)&As[(wm + i * 16 + fm) * GTK + q * 8];
#pragma unroll
        for (int j = 0; j < 4; ++j)
            bfr[j] = *(short8*)&Bs[(wn + j * 16 + fm) * GTK + q * 8];
#pragma unroll
        for (int i = 0; i < 4; ++i)
#pragma unroll
            for (int j = 0; j < 4; ++j)
                acc[i][j] = __builtin_amdgcn_mfma_f32_16x16x32_bf16(
                    af[i], bfr[j], acc[i][j], 0, 0, 0);
        __syncthreads();
    }

    // C/D layout: col=lane&15, row=(lane>>4)*4+reg  [m89/m91-verified]
    const int col = lane & 15;
    const int rq  = (lane >> 4) * 4;
#pragma unroll
    for (int i = 0; i < 4; ++i) {
#pragma unroll
        for (int j = 0; j < 4; ++j) {
#pragma unroll
            for (int r = 0; r < 4; ++r) {
                const int gm = bm + wm + i * 16 + rq + r;
                const int gn = bn + wn + j * 16 + col;
                if (gn >= N) continue;
                float v = acc[i][j][r];
                if constexpr (EPI == 0) {
                    C[(size_t)blockIdx.z * BL * D_MODEL +
                      (size_t)gm * ldc + gn] = v;
                } else if constexpr (EPI == 3) {
                    atomicAdd(&C[(size_t)gm * ldc + gn], v);
                } else if constexpr (EPI == 4) {
                    if (gn < D_INNER) C[(size_t)gm * ldc + gn] = v;
                    else C2[(size_t)gm * (size_t)D_INNER + (gn - D_INNER)] = f2b(v);
                } else {  // EPI == 5
                    C2[(size_t)gm * ldc + gn] = f2b(fsoftp(v + bias[gn]));
                }
            }
        }
    }
}

// ------------- conv(4)+SiLU: reads fp32 uraw, writes bf16 uc -----------------
__global__ __launch_bounds__(256) void conv_par3(
    const float* __restrict__ uraw, const float* __restrict__ cw,
    const float* __restrict__ cb, bf16* __restrict__ ucb)
{
    const int id = blockIdx.x * 256 + threadIdx.x;  // = (b*LL+t)*D_INNER+d
    const int d = id & (D_INNER - 1);
    const int t = (id >> 11) & (LL - 1);
    float acc = cb[d];
#pragma unroll
    for (int k = 0; k < 4; ++k) {
        const int tt = t - 3 + k;
        if (tt >= 0)
            acc += uraw[(size_t)id + (size_t)(k - 3) * D_INNER] * cw[d * 4 + k];
    }
    ucb[id] = f2b(acc * fsig(acc));
}

// ------------- dbl[:, :64] -> bf16 dt_r copy for GEMM-5 ----------------------
__global__ __launch_bounds__(256) void cvt_dtr(
    const float* __restrict__ dbl, bf16* __restrict__ dtr_bf)
{
    const int id = blockIdx.x * 256 + threadIdx.x;  // m*64+r
    const int m = id >> 6, r = id & 63;
    dtr_bf[id] = f2b(dbl[(size_t)m * DBL_LD + r]);
}

// ------------------------------ 3-phase scan ---------------------------------
// block decode: blk = ((b*NCH)+c)*8 + dgrp ; d = dgrp*256 + tid
__global__ __launch_bounds__(256) void scan_p1(
    const bf16* __restrict__ uc, const bf16* __restrict__ dtb,
    const float* __restrict__ dbl, const float* __restrict__ A_log,
    float* __restrict__ Psum, float* __restrict__ Hloc)
{
    const int blk = blockIdx.x;
    const int d = (blk & 7) * 256 + threadIdx.x;
    const int c = (blk >> 3) & (NCH - 1);
    const int b = blk >> 9;                  // NCH=64 -> 9 bits below b
    float A[D_STATE], h[D_STATE];
#pragma unroll
    for (int n = 0; n < D_STATE; ++n) {
        A[n] = -__expf(A_log[d * D_STATE + n]);
        h[n] = 0.f;
    }
    const size_t row0 = (size_t)b * LL + c * TCH;
    const bf16* dtp = dtb + row0 * D_INNER + d;
    const bf16* up  = uc  + row0 * D_INNER + d;
    const float* Bp = dbl + row0 * DBL_LD + DT_RANK;
    float S = 0.f;
    for (int t = 0; t < TCH; ++t) {
        const float dtv = (float)dtp[(size_t)t * D_INNER];
        const float uv  = (float)up[(size_t)t * D_INNER];
        const float du  = dtv * uv;
        S += dtv;
#pragma unroll
        for (int n = 0; n < D_STATE; ++n)
            h[n] = __expf(dtv * A[n]) * h[n] + du * Bp[(size_t)t * DBL_LD + n];
    }
    const size_t o = (((size_t)b * NCH + c) * D_INNER + d) * D_STATE;
#pragma unroll
    for (int n = 0; n < D_STATE; ++n) {
        Psum[o + n] = __expf(S * A[n]);
        Hloc[o + n] = h[n];
    }
}

__global__ __launch_bounds__(256) void scan_p2(
    float* __restrict__ Psum, const float* __restrict__ Hloc)
{
    const int id = blockIdx.x * 256 + threadIdx.x;
    const int dn = id & (D_INNER * D_STATE - 1);
    const int b  = id >> 15;
    float h = 0.f;
    for (int c = 0; c < NCH; ++c) {
        const size_t o = ((size_t)(b * NCH + c) * D_INNER * D_STATE) + dn;
        const float P  = Psum[o];
        const float hl = Hloc[o];
        Psum[o] = h;          // Hin for chunk c
        h = P * h + hl;
    }
}

// phase 3: replay; bf16 u (ucy), bf16 dt, bf16 z (zbf); y overwrites ucy
__global__ __launch_bounds__(256) void scan_p3b(
    bf16* __restrict__ ucy, const bf16* __restrict__ dtb,
    const float* __restrict__ dbl, const float* __restrict__ A_log,
    const float* __restrict__ Dw, const float* __restrict__ Hin,
    const bf16* __restrict__ zbf)
{
    const int blk = blockIdx.x;
    const int d = (blk & 7) * 256 + threadIdx.x;
    const int c = (blk >> 3) & (NCH - 1);
    const int b = blk >> 9;                  // NCH=64 -> 9 bits below b
    float A[D_STATE], h[D_STATE];
    const size_t o = (((size_t)b * NCH + c) * D_INNER + d) * D_STATE;
#pragma unroll
    for (int n = 0; n < D_STATE; ++n) {
        A[n] = -__expf(A_log[d * D_STATE + n]);
        h[n] = Hin[o + n];
    }
    const float Dd = Dw[d];
    const size_t row0 = (size_t)b * LL + c * TCH;
    const bf16* dtp = dtb + row0 * D_INNER + d;
    bf16*       uyp = ucy + row0 * D_INNER + d;     // u in, y out (same slot)
    const float* BCp = dbl + row0 * DBL_LD;
    const bf16* zp   = zbf + row0 * D_INNER + d;
    for (int t = 0; t < TCH; ++t) {
        const float dtv = (float)dtp[(size_t)t * D_INNER];
        const float uv  = (float)uyp[(size_t)t * D_INNER];
        const float du  = dtv * uv;
        float acc = uv * Dd;
        const float* Brow = BCp + (size_t)t * DBL_LD + DT_RANK;
        const float* Crow = Brow + D_STATE;
#pragma unroll
        for (int n = 0; n < D_STATE; ++n) {
            h[n] = __expf(dtv * A[n]) * h[n] + du * Brow[n];
            acc += h[n] * Crow[n];
        }
        const float zv = (float)zp[(size_t)t * D_INNER];
        uyp[(size_t)t * D_INNER] = f2b(acc * zv * fsig(zv));
    }
}

// ---------------- fallback (small ws): R4 sequential path --------------------
#define BM 128
#define BN 128
#define BK 8

__global__ __launch_bounds__(256) void ln_kernel(
    const float* __restrict__ x, const float* __restrict__ w,
    const float* __restrict__ b, float* __restrict__ xnf)
{
    __shared__ float s1[256], s2[256];
    const int row = blockIdx.x;
    const int tid = threadIdx.x;
    const float* xr = x + (size_t)row * D_MODEL;
    float v[4], sum = 0.f, sq = 0.f;
#pragma unroll
    for (int i = 0; i < 4; ++i) {
        v[i] = xr[tid + 256 * i];
        sum += v[i];
        sq  += v[i] * v[i];
    }
    s1[tid] = sum; s2[tid] = sq;
    __syncthreads();
    for (int s = 128; s > 0; s >>= 1) {
        if (tid < s) { s1[tid] += s1[tid + s]; s2[tid] += s2[tid + s]; }
        __syncthreads();
    }
    const float mu  = s1[0] * (1.f / D_MODEL);
    const float var = s2[0] * (1.f / D_MODEL) - mu * mu;
    const float rs  = rsqrtf(var + 1e-5f);
#pragma unroll
    for (int i = 0; i < 4; ++i) {
        const int c = tid + 256 * i;
        xnf[(size_t)row * D_MODEL + c] = (v[i] - mu) * rs * w[c] + b[c];
    }
}

__global__ __launch_bounds__(256) void gemm_bt(
    const float* __restrict__ A, int lda,
    const float* __restrict__ Bw,
    float* __restrict__ C, int ldc,
    int M, int N, int K, int epi,
    const float* __restrict__ bias,
    const float* __restrict__ resid)
{
    __shared__ float As[BK][BM + 1];
    __shared__ float Bs[BK][BN + 1];
    const int tx = threadIdx.x, ty = threadIdx.y;
    const int tid = ty * 16 + tx;
    const int bm = blockIdx.y * BM, bn = blockIdx.x * BN;
    float acc[8][8];
#pragma unroll
    for (int i = 0; i < 8; ++i)
#pragma unroll
        for (int j = 0; j < 8; ++j) acc[i][j] = 0.f;
    for (int k0 = 0; k0 < K; k0 += BK) {
#pragma unroll
        for (int i = tid; i < BM * BK; i += 256) {
            const int m = i / BK, kk = i % BK;
            As[kk][m] = A[(size_t)(bm + m) * lda + (k0 + kk)];
        }
#pragma unroll
        for (int i = tid; i < BN * BK; i += 256) {
            const int n = i / BK, kk = i % BK;
            const int gn = bn + n;
            Bs[kk][n] = (gn < N) ? Bw[(size_t)gn * K + (k0 + kk)] : 0.f;
        }
        __syncthreads();
#pragma unroll
        for (int kk = 0; kk < BK; ++kk) {
            float av[8], bv[8];
#pragma unroll
            for (int i = 0; i < 8; ++i) av[i] = As[kk][ty * 8 + i];
#pragma unroll
            for (int j = 0; j < 8; ++j) bv[j] = Bs[kk][tx * 8 + j];
#pragma unroll
            for (int i = 0; i < 8; ++i)
#pragma unroll
                for (int j = 0; j < 8; ++j) acc[i][j] += av[i] * bv[j];
        }
        __syncthreads();
    }
#pragma unroll
    for (int i = 0; i < 8; ++i) {
        const int gm = bm + ty * 8 + i;
#pragma unroll
        for (int j = 0; j < 8; ++j) {
            const int gn = bn + tx * 8 + j;
            if (gn >= N) continue;
            float v = acc[i][j];
            if (epi == 1) {
                v += bias[gn];
                v = fmaxf(v, 0.f) + log1pf(expf(-fabsf(v)));
            } else if (epi == 2) {
                v += resid[(size_t)gm * ldc + gn];
            }
            C[(size_t)gm * ldc + gn] = v;
        }
    }
}

__global__ __launch_bounds__(256) void conv_silu_kernel(
    float* __restrict__ xz, const float* __restrict__ cw,
    const float* __restrict__ cb)
{
    const int idx = blockIdx.x * 256 + threadIdx.x;
    const int b = idx >> 11, d = idx & (D_INNER - 1);
    const float w0 = cw[d * 4 + 0], w1 = cw[d * 4 + 1];
    const float w2 = cw[d * 4 + 2], w3 = cw[d * 4 + 3];
    const float bias = cb[d];
    float* u = xz + (size_t)b * LL * XZ_LD + d;
    float x0 = 0.f, x1 = 0.f, x2 = 0.f;
    for (int t = 0; t < LL; ++t) {
        const float x3 = u[(size_t)t * XZ_LD];
        const float c = bias + x0 * w0 + x1 * w1 + x2 * w2 + x3 * w3;
        u[(size_t)t * XZ_LD] = c / (1.f + expf(-c));
        x0 = x1; x1 = x2; x2 = x3;
    }
}

__global__ __launch_bounds__(256) void scan_kernel(
    float* __restrict__ xz, const float* __restrict__ dtb,
    const float* __restrict__ dbl,
    const float* __restrict__ A_log, const float* __restrict__ Dw)
{
    const int idx = blockIdx.x * 256 + threadIdx.x;
    const int b = idx >> 11, d = idx & (D_INNER - 1);
    float A[D_STATE], h[D_STATE];
#pragma unroll
    for (int n = 0; n < D_STATE; ++n) {
        A[n] = -expf(A_log[d * D_STATE + n]);
        h[n] = 0.f;
    }
    const float Dd = Dw[d];
    const float* dtp  = dtb + (size_t)b * LL * D_INNER + d;
    float*       up   = xz  + (size_t)b * LL * XZ_LD + d;
    const float* dblp = dbl + (size_t)b * LL * DBL_LD;
    for (int t = 0; t < LL; ++t) {
        const float dtv = dtp[(size_t)t * D_INNER];
        const float uv  = up[(size_t)t * XZ_LD];
        const float zv  = up[(size_t)t * XZ_LD + D_INNER];
        const float* Brow = dblp + (size_t)t * DBL_LD + DT_RANK;
        const float* Crow = Brow + D_STATE;
        const float du = dtv * uv;
        float acc = uv * Dd;
#pragma unroll
        for (int n = 0; n < D_STATE; ++n) {
            const float dA = expf(dtv * A[n]);
            h[n] = dA * h[n] + du * Brow[n];
            acc += h[n] * Crow[n];
        }
        const float sz = zv / (1.f + expf(-zv));
        up[(size_t)t * XZ_LD] = acc * sz;
    }
}

extern "C" void kernel_launch(void* const* d_in, const int* in_sizes, int n_in,
                              void* d_out, int out_size, void* d_ws, size_t ws_size,
                              hipStream_t stream)
{
    const float* x       = (const float*)d_in[0];
    const float* ln_w    = (const float*)d_in[1];
    const float* ln_b    = (const float*)d_in[2];
    const float* W_in    = (const float*)d_in[3];
    const float* conv_w  = (const float*)d_in[4];
    const float* conv_b  = (const float*)d_in[5];
    const float* W_xproj = (const float*)d_in[6];
    const float* W_dt    = (const float*)d_in[7];
    const float* b_dt    = (const float*)d_in[8];
    const float* A_log   = (const float*)d_in[9];
    const float* Dw      = (const float*)d_in[10];
    const float* W_out   = (const float*)d_in[11];
    float* out = (float*)d_out;

    // ws layout identical to R15/R16 (134.8 MiB, each size audited):
    //   dtb_bf [0,        4194304)   bf16 dt 4096x2048
    //   uraw   [4194304, 12582912)   fp32 u  4096x2048
    //   zbf    [12582912, 16777216)  bf16 z  4096x2048
    //   Psum   [16777216, 20971520)  fp32; later G7 slab 0
    //   Hloc   [20971520, 25165824)  fp32; later G7 slab 1
    //   dbl    [25165824, 25559040)  fp32 4096x96
    //   ucy    [25559040, 29753344)  bf16 conv(u) then y
    //   xn_bf  [29753344, 31850496)  bf16 4096x1024
    //   win_bf [31850496, 33947648)  bf16 4096x1024
    //   wx_bf  [33947648, 34078720) | wdt_bf [34078720, 34144256)
    //   wout_bf[34144256, 35192832) | dtr_bf [35192832, 35323904)
    float* wsf     = (float*)d_ws;
    bf16*  dtb_bf  = (bf16*)wsf;
    float* uraw    = wsf + 4194304;
    bf16*  zbf     = (bf16*)(wsf + 12582912);
    float* Psum    = wsf + 16777216;       // G7 slabs are contiguous here
    float* Hloc    = wsf + 20971520;
    float* dbl     = wsf + 25165824;
    bf16*  ucy     = (bf16*)(wsf + 25559040);
    bf16*  xn_bf   = (bf16*)(wsf + 29753344);
    bf16*  win_bf  = (bf16*)(wsf + 31850496);
    bf16*  wx_bf   = (bf16*)(wsf + 33947648);
    bf16*  wdt_bf  = (bf16*)(wsf + 34078720);
    bf16*  wout_bf = (bf16*)(wsf + 34144256);
    bf16*  dtr_bf  = (bf16*)(wsf + 35192832);
    const size_t need_big = (size_t)35323904 * sizeof(float);

    if (ws_size >= need_big) {
        wcvt_kernel<<<WCVT_TOT / 256, 256, 0, stream>>>(
            W_in, W_xproj, W_dt, W_out, win_bf, wx_bf, wdt_bf, wout_bf, dbl);
        ln_kernel_bf<<<BL, 256, 0, stream>>>(x, ln_w, ln_b, xn_bf);
        // G2: [u|z] = xn @ W_in^T; u -> fp32 uraw, z -> bf16 zbf  [EPI=4]
        gemm_t<4><<<dim3(XZ_LD / GTN, BL / GTM, 1), 256, 0, stream>>>(
            xn_bf, D_MODEL, win_bf, D_MODEL, uraw, D_INNER,
            XZ_LD, D_MODEL, nullptr, zbf);
        // conv+SiLU: fp32 u -> bf16 uc
        conv_par3<<<(size_t)BL * D_INNER / 256, 256, 0, stream>>>(
            uraw, conv_w, conv_b, ucy);
        // G4: dbl += uc @ W_xproj^T  (N=96 pad 128, split-K=8)  [EPI=3 atomic]
        gemm_t<3><<<dim3(1, BL / GTM, 8), 256, 0, stream>>>(
            ucy, D_INNER, wx_bf, D_INNER, dbl, DBL_LD,
            DBL_LD, D_INNER / 8, nullptr, nullptr);
        cvt_dtr<<<BL * DT_RANK / 256, 256, 0, stream>>>(dbl, dtr_bf);
        // G5: dt = softplus(dt_r @ W_dt^T + b_dt), bf16 store  [EPI=5]
        gemm_t<5><<<dim3(D_INNER / GTN, BL / GTM, 1), 256, 0, stream>>>(
            dtr_bf, DT_RANK, wdt_bf, DT_RANK, nullptr, D_INNER,
            D_INNER, DT_RANK, b_dt, dtb_bf);
        // chunked scan, NCH=64
        scan_p1<<<BB * NCH * 8, 256, 0, stream>>>(
            ucy, dtb_bf, dbl, A_log, Psum, Hloc);
        scan_p2<<<BB * D_INNER * D_STATE / 256, 256, 0, stream>>>(Psum, Hloc);
        scan_p3b<<<BB * NCH * 8, 256, 0, stream>>>(
            ucy, dtb_bf, dbl, A_log, Dw, Psum, zbf);
        // G7: partials = y @ W_out^T  (split-K=2 into Psum/Hloc slabs) [EPI=0]
        gemm_t<0><<<dim3(D_MODEL / GTN, BL / GTM, 2), 256, 0, stream>>>(
            ucy, D_INNER, wout_bf, D_INNER, Psum, D_MODEL,
            D_MODEL, D_INNER / 2, nullptr, nullptr);
        // out = x + p0 + p1
        reduce_out<<<BL * D_MODEL / 4 / 256, 256, 0, stream>>>(
            x, Psum, Hloc, out);
    } else {
        float* fdtb = wsf;
        float* fxn  = fdtb;
        float* fxz  = fdtb + (size_t)BL * D_INNER;
        float* fdbl = fxz + (size_t)BL * XZ_LD;
        ln_kernel<<<BL, 256, 0, stream>>>(x, ln_w, ln_b, fxn);
        dim3 blk(16, 16);
        gemm_bt<<<dim3(XZ_LD / BN, BL / BM), blk, 0, stream>>>(
            fxn, D_MODEL, W_in, fxz, XZ_LD, BL, XZ_LD, D_MODEL, 0, nullptr, nullptr);
        conv_silu_kernel<<<(BB * D_INNER) / 256, 256, 0, stream>>>(fxz, conv_w, conv_b);
        gemm_bt<<<dim3(1, BL / BM), blk, 0, stream>>>(
            fxz, XZ_LD, W_xproj, fdbl, DBL_LD, BL, DBL_LD, D_INNER, 0, nullptr, nullptr);
        gemm_bt<<<dim3(D_INNER / BN, BL / BM), blk, 0, stream>>>(
            fdbl, DBL_LD, W_dt, fdtb, D_INNER, BL, D_INNER, DT_RANK, 1, b_dt, nullptr);
        scan_kernel<<<(BB * D_INNER) / 256, 256, 0, stream>>>(fxz, fdtb, fdbl, A_log, Dw);
        gemm_bt<<<dim3(D_MODEL / BN, BL / BM), blk, 0, stream>>>(
            fxz, XZ_LD, W_out, out, D_MODEL, BL, D_MODEL, D_INNER, 2, nullptr, x);
    }
}

// Round 18
// 353.265 us; speedup vs baseline: 1.1162x; 1.0491x over previous
//
#include <hip/hip_runtime.h>
#include <hip/hip_bf16.h>
#include <stdint.h>

typedef __hip_bfloat16 bf16;
typedef __attribute__((ext_vector_type(8))) short short8;
typedef __attribute__((ext_vector_type(4))) float floatx4;

#define D_MODEL 1024
#define D_STATE 16
#define D_INNER 2048
#define DT_RANK 64
#define BB 2
#define LL 2048
#define BL (BB * LL)            // 4096 rows
#define XZ_LD (2 * D_INNER)     // 4096 (fallback path only)
#define DBL_LD (DT_RANK + 2 * D_STATE)  // 96
#define NCH 64                  // time chunks for parallel scan
#define TCH (LL / NCH)          // 32 steps per chunk

__device__ __forceinline__ bf16 f2b(float f) { return __float2bfloat16(f); }

// fast sigmoid / softplus via native v_exp/v_log/v_rcp (~3e-7 rel err)
__device__ __forceinline__ float fsig(float v)  { return __fdividef(1.f, 1.f + __expf(-v)); }
__device__ __forceinline__ float fsoftp(float v){ return fmaxf(v, 0.f) + __logf(1.f + __expf(-fabsf(v))); }

// async 16B global -> LDS (wave-uniform LDS base + lane*16; rows contiguous)
__device__ __forceinline__ void gload16(const void* g, void* l) {
    __builtin_amdgcn_global_load_lds(
        (const __attribute__((address_space(1))) uint32_t*)(uintptr_t)g,
        (__attribute__((address_space(3))) uint32_t*)(uintptr_t)l,
        16, 0, 0);
}

#define S0 (4096 * 1024)   // W_in
#define S1 (128 * 2048)    // W_xproj padded to 128 rows
#define S2 (2048 * 64)     // W_dt
#define S3 (1024 * 2048)   // W_out
#define S4 (BL * DBL_LD)   // dbl zero-init (for split-K atomics)
#define WCVT_TOT (S0 + S1 + S2 + S3 + S4)

// --------- weight conversion (+pad W_xproj, +zero dbl) — runs FIRST ---------
__global__ __launch_bounds__(256) void wcvt_kernel(
    const float* __restrict__ Win, const float* __restrict__ Wx,
    const float* __restrict__ Wdt, const float* __restrict__ Wout,
    bf16* __restrict__ win_bf, bf16* __restrict__ wx_bf,
    bf16* __restrict__ wdt_bf, bf16* __restrict__ wout_bf,
    float* __restrict__ dbl)
{
    int id = blockIdx.x * 256 + threadIdx.x;
    if (id < S0) { win_bf[id] = f2b(Win[id]); return; }
    id -= S0;
    if (id < S1) { wx_bf[id] = (id < 96 * 2048) ? f2b(Wx[id]) : f2b(0.f); return; }
    id -= S1;
    if (id < S2) { wdt_bf[id] = f2b(Wdt[id]); return; }
    id -= S2;
    if (id < S3) { wout_bf[id] = f2b(Wout[id]); return; }
    id -= S3;
    dbl[id] = 0.f;
}

// ---------------- LayerNorm: one block per row; bf16 out ---------------------
__global__ __launch_bounds__(256) void ln_kernel_bf(
    const float* __restrict__ x, const float* __restrict__ w,
    const float* __restrict__ b, bf16* __restrict__ xnb)
{
    __shared__ float s1[256], s2[256];
    const int row = blockIdx.x;
    const int tid = threadIdx.x;
    const float* xr = x + (size_t)row * D_MODEL;
    float v[4], sum = 0.f, sq = 0.f;
#pragma unroll
    for (int i = 0; i < 4; ++i) {
        v[i] = xr[tid + 256 * i];
        sum += v[i];
        sq  += v[i] * v[i];
    }
    s1[tid] = sum; s2[tid] = sq;
    __syncthreads();
    for (int s = 128; s > 0; s >>= 1) {
        if (tid < s) { s1[tid] += s1[tid + s]; s2[tid] += s2[tid + s]; }
        __syncthreads();
    }
    const float mu  = s1[0] * (1.f / D_MODEL);
    const float var = s2[0] * (1.f / D_MODEL) - mu * mu;
    const float rs  = rsqrtf(var + 1e-5f);
#pragma unroll
    for (int i = 0; i < 4; ++i) {
        const int c = tid + 256 * i;
        xnb[(size_t)row * D_MODEL + c] = f2b((v[i] - mu) * rs * w[c] + b[c]);
    }
}

// ------------- final reduce: out = x + p0 + p1 (float4) ----------------------
__global__ __launch_bounds__(256) void reduce_out(
    const float* __restrict__ x, const float* __restrict__ p0,
    const float* __restrict__ p1, float* __restrict__ out)
{
    const int id = blockIdx.x * 256 + threadIdx.x;
    const float4 a = ((const float4*)x)[id];
    const float4 u = ((const float4*)p0)[id];
    const float4 v = ((const float4*)p1)[id];
    float4 r;
    r.x = a.x + u.x + v.x; r.y = a.y + u.y + v.y;
    r.z = a.z + u.z + v.z; r.w = a.w + u.w + v.w;
    ((float4*)out)[id] = r;
}

// ===== bf16 MFMA GEMM, compile-time-specialized epilogues (R17-proven) =======
// EPI: 0=slab fp32 store (+blockIdx.z*BL*D_MODEL); 3=atomicAdd;
// 4=u/z split (gn<D_INNER -> fp32 C else bf16 C2); 5=softplus bf16 -> C2.
#define GTM 128
#define GTN 128
#define GTK 32

template <int EPI>
__global__ __launch_bounds__(256) void gemm_t(
    const bf16* __restrict__ A, int lda,
    const bf16* __restrict__ B, int ldb,
    float* __restrict__ C, int ldc,
    int N, int K,
    const float* __restrict__ bias,
    bf16* __restrict__ C2)
{
    __shared__ short As[GTM * GTK];   // 8 KB
    __shared__ short Bs[GTN * GTK];   // 8 KB
    const int tid  = threadIdx.x;
    const int lane = tid & 63;
    const int wave = tid >> 6;            // 0..3
    const int wm = (wave & 1) * 64;
    const int wn = (wave >> 1) * 64;
    const int bm = blockIdx.y * GTM;
    const int bn = blockIdx.x * GTN;
    const int kbase = blockIdx.z * K;     // split-K base (K = slice length)

    floatx4 acc[4][4];
#pragma unroll
    for (int i = 0; i < 4; ++i)
#pragma unroll
        for (int j = 0; j < 4; ++j) acc[i][j] = (floatx4){0.f, 0.f, 0.f, 0.f};

    const int srow = wave * 16 + (lane >> 2);   // 0..63 (per pass)
    const int scol = (lane & 3) * 8;            // bf16 col within k-tile
    const int fm = lane & 15;
    const int q  = lane >> 4;

    for (int k0 = 0; k0 < K; k0 += GTK) {
#pragma unroll
        for (int r = 0; r < 2; ++r) {
            const int m = r * 64 + srow;
            gload16(A + (size_t)(bm + m) * lda + kbase + k0 + scol,
                    As + m * GTK + scol);
            gload16(B + (size_t)(bn + m) * ldb + kbase + k0 + scol,
                    Bs + m * GTK + scol);
        }
        __syncthreads();

        short8 af[4], bfr[4];
#pragma unroll
        for (int i = 0; i < 4; ++i)
            af[i] = *(short8*)&As[(wm + i * 16 + fm) * GTK + q * 8];
#pragma unroll
        for (int j = 0; j < 4; ++j)
            bfr[j] = *(short8*)&Bs[(wn + j * 16 + fm) * GTK + q * 8];
#pragma unroll
        for (int i = 0; i < 4; ++i)
#pragma unroll
            for (int j = 0; j < 4; ++j)
                acc[i][j] = __builtin_amdgcn_mfma_f32_16x16x32_bf16(
                    af[i], bfr[j], acc[i][j], 0, 0, 0);
        __syncthreads();
    }

    // C/D layout: col=lane&15, row=(lane>>4)*4+reg  [m89/m91-verified]
    const int col = lane & 15;
    const int rq  = (lane >> 4) * 4;
#pragma unroll
    for (int i = 0; i < 4; ++i) {
#pragma unroll
        for (int j = 0; j < 4; ++j) {
#pragma unroll
            for (int r = 0; r < 4; ++r) {
                const int gm = bm + wm + i * 16 + rq + r;
                const int gn = bn + wn + j * 16 + col;
                if (gn >= N) continue;
                float v = acc[i][j][r];
                if constexpr (EPI == 0) {
                    C[(size_t)blockIdx.z * BL * D_MODEL +
                      (size_t)gm * ldc + gn] = v;
                } else if constexpr (EPI == 3) {
                    atomicAdd(&C[(size_t)gm * ldc + gn], v);
                } else if constexpr (EPI == 4) {
                    if (gn < D_INNER) C[(size_t)gm * ldc + gn] = v;
                    else C2[(size_t)gm * (size_t)D_INNER + (gn - D_INNER)] = f2b(v);
                } else {  // EPI == 5
                    C2[(size_t)gm * ldc + gn] = f2b(fsoftp(v + bias[gn]));
                }
            }
        }
    }
}

// ------------- conv(4)+SiLU: reads fp32 uraw, writes bf16 uc -----------------
__global__ __launch_bounds__(256) void conv_par3(
    const float* __restrict__ uraw, const float* __restrict__ cw,
    const float* __restrict__ cb, bf16* __restrict__ ucb)
{
    const int id = blockIdx.x * 256 + threadIdx.x;  // = (b*LL+t)*D_INNER+d
    const int d = id & (D_INNER - 1);
    const int t = (id >> 11) & (LL - 1);
    float acc = cb[d];
#pragma unroll
    for (int k = 0; k < 4; ++k) {
        const int tt = t - 3 + k;
        if (tt >= 0)
            acc += uraw[(size_t)id + (size_t)(k - 3) * D_INNER] * cw[d * 4 + k];
    }
    ucb[id] = f2b(acc * fsig(acc));
}

// ------------- dbl[:, :64] -> bf16 dt_r copy for GEMM-5 ----------------------
__global__ __launch_bounds__(256) void cvt_dtr(
    const float* __restrict__ dbl, bf16* __restrict__ dtr_bf)
{
    const int id = blockIdx.x * 256 + threadIdx.x;  // m*64+r
    const int m = id >> 6, r = id & 63;
    dtr_bf[id] = f2b(dbl[(size_t)m * DBL_LD + r]);
}

// ------------------------------ 3-phase scan ---------------------------------
// The reference constructs A_log = log(broadcast(arange(1..16))), so
// A[n] = -(n+1) exactly -> exp(dt*A[n]) = e1^(n+1), e1 = exp(-dt): 1 exp +
// 15 muls instead of 16 exps per timestep (v_exp is quarter-rate). Verified
// per-thread at init (uniform flag); general fallback otherwise.
// block decode: blk = ((b*NCH)+c)*8 + dgrp ; d = dgrp*256 + tid
__global__ __launch_bounds__(256) void scan_p1(
    const bf16* __restrict__ uc, const bf16* __restrict__ dtb,
    const float* __restrict__ dbl, const float* __restrict__ A_log,
    float* __restrict__ Psum, float* __restrict__ Hloc)
{
    const int blk = blockIdx.x;
    const int d = (blk & 7) * 256 + threadIdx.x;
    const int c = (blk >> 3) & (NCH - 1);
    const int b = blk >> 9;                  // NCH=64 -> 9 bits below b
    float A[D_STATE], h[D_STATE];
    bool lin = true;
#pragma unroll
    for (int n = 0; n < D_STATE; ++n) {
        A[n] = -__expf(A_log[d * D_STATE + n]);
        lin = lin && (fabsf(A[n] + (float)(n + 1)) < 1e-3f);
        h[n] = 0.f;
    }
    const size_t row0 = (size_t)b * LL + c * TCH;
    const bf16* dtp = dtb + row0 * D_INNER + d;
    const bf16* up  = uc  + row0 * D_INNER + d;
    const float* Bp = dbl + row0 * DBL_LD + DT_RANK;
    float S = 0.f;
    if (lin) {
        for (int t = 0; t < TCH; ++t) {
            const float dtv = (float)dtp[(size_t)t * D_INNER];
            const float uv  = (float)up[(size_t)t * D_INNER];
            const float du  = dtv * uv;
            S += dtv;
            const float e1 = __expf(-dtv);
            float dA = 1.f;
#pragma unroll
            for (int n = 0; n < D_STATE; ++n) {
                dA *= e1;                       // e1^(n+1)
                h[n] = dA * h[n] + du * Bp[(size_t)t * DBL_LD + n];
            }
        }
    } else {
        for (int t = 0; t < TCH; ++t) {
            const float dtv = (float)dtp[(size_t)t * D_INNER];
            const float uv  = (float)up[(size_t)t * D_INNER];
            const float du  = dtv * uv;
            S += dtv;
#pragma unroll
            for (int n = 0; n < D_STATE; ++n)
                h[n] = __expf(dtv * A[n]) * h[n] + du * Bp[(size_t)t * DBL_LD + n];
        }
    }
    const size_t o = (((size_t)b * NCH + c) * D_INNER + d) * D_STATE;
    if (lin) {
        const float E1 = __expf(-S);
        float P = 1.f;
#pragma unroll
        for (int n = 0; n < D_STATE; ++n) {
            P *= E1;
            Psum[o + n] = P;
            Hloc[o + n] = h[n];
        }
    } else {
#pragma unroll
        for (int n = 0; n < D_STATE; ++n) {
            Psum[o + n] = __expf(S * A[n]);
            Hloc[o + n] = h[n];
        }
    }
}

__global__ __launch_bounds__(256) void scan_p2(
    float* __restrict__ Psum, const float* __restrict__ Hloc)
{
    const int id = blockIdx.x * 256 + threadIdx.x;
    const int dn = id & (D_INNER * D_STATE - 1);
    const int b  = id >> 15;
    float h = 0.f;
    for (int c = 0; c < NCH; ++c) {
        const size_t o = ((size_t)(b * NCH + c) * D_INNER * D_STATE) + dn;
        const float P  = Psum[o];
        const float hl = Hloc[o];
        Psum[o] = h;          // Hin for chunk c
        h = P * h + hl;
    }
}

// phase 3: replay; bf16 u (ucy), bf16 dt, bf16 z (zbf); y overwrites ucy
__global__ __launch_bounds__(256) void scan_p3b(
    bf16* __restrict__ ucy, const bf16* __restrict__ dtb,
    const float* __restrict__ dbl, const float* __restrict__ A_log,
    const float* __restrict__ Dw, const float* __restrict__ Hin,
    const bf16* __restrict__ zbf)
{
    const int blk = blockIdx.x;
    const int d = (blk & 7) * 256 + threadIdx.x;
    const int c = (blk >> 3) & (NCH - 1);
    const int b = blk >> 9;                  // NCH=64 -> 9 bits below b
    float A[D_STATE], h[D_STATE];
    const size_t o = (((size_t)b * NCH + c) * D_INNER + d) * D_STATE;
    bool lin = true;
#pragma unroll
    for (int n = 0; n < D_STATE; ++n) {
        A[n] = -__expf(A_log[d * D_STATE + n]);
        lin = lin && (fabsf(A[n] + (float)(n + 1)) < 1e-3f);
        h[n] = Hin[o + n];
    }
    const float Dd = Dw[d];
    const size_t row0 = (size_t)b * LL + c * TCH;
    const bf16* dtp = dtb + row0 * D_INNER + d;
    bf16*       uyp = ucy + row0 * D_INNER + d;     // u in, y out (same slot)
    const float* BCp = dbl + row0 * DBL_LD;
    const bf16* zp   = zbf + row0 * D_INNER + d;
    if (lin) {
        for (int t = 0; t < TCH; ++t) {
            const float dtv = (float)dtp[(size_t)t * D_INNER];
            const float uv  = (float)uyp[(size_t)t * D_INNER];
            const float du  = dtv * uv;
            float acc = uv * Dd;
            const float* Brow = BCp + (size_t)t * DBL_LD + DT_RANK;
            const float* Crow = Brow + D_STATE;
            const float e1 = __expf(-dtv);
            float dA = 1.f;
#pragma unroll
            for (int n = 0; n < D_STATE; ++n) {
                dA *= e1;                       // e1^(n+1)
                h[n] = dA * h[n] + du * Brow[n];
                acc += h[n] * Crow[n];
            }
            const float zv = (float)zp[(size_t)t * D_INNER];
            uyp[(size_t)t * D_INNER] = f2b(acc * zv * fsig(zv));
        }
    } else {
        for (int t = 0; t < TCH; ++t) {
            const float dtv = (float)dtp[(size_t)t * D_INNER];
            const float uv  = (float)uyp[(size_t)t * D_INNER];
            const float du  = dtv * uv;
            float acc = uv * Dd;
            const float* Brow = BCp + (size_t)t * DBL_LD + DT_RANK;
            const float* Crow = Brow + D_STATE;
#pragma unroll
            for (int n = 0; n < D_STATE; ++n) {
                h[n] = __expf(dtv * A[n]) * h[n] + du * Brow[n];
                acc += h[n] * Crow[n];
            }
            const float zv = (float)zp[(size_t)t * D_INNER];
            uyp[(size_t)t * D_INNER] = f2b(acc * zv * fsig(zv));
        }
    }
}

// ---------------- fallback (small ws): R4 sequential path --------------------
#define BM 128
#define BN 128
#define BK 8

__global__ __launch_bounds__(256) void ln_kernel(
    const float* __restrict__ x, const float* __restrict__ w,
    const float* __restrict__ b, float* __restrict__ xnf)
{
    __shared__ float s1[256], s2[256];
    const int row = blockIdx.x;
    const int tid = threadIdx.x;
    const float* xr = x + (size_t)row * D_MODEL;
    float v[4], sum = 0.f, sq = 0.f;
#pragma unroll
    for (int i = 0; i < 4; ++i) {
        v[i] = xr[tid + 256 * i];
        sum += v[i];
        sq  += v[i] * v[i];
    }
    s1[tid] = sum; s2[tid] = sq;
    __syncthreads();
    for (int s = 128; s > 0; s >>= 1) {
        if (tid < s) { s1[tid] += s1[tid + s]; s2[tid] += s2[tid + s]; }
        __syncthreads();
    }
    const float mu  = s1[0] * (1.f / D_MODEL);
    const float var = s2[0] * (1.f / D_MODEL) - mu * mu;
    const float rs  = rsqrtf(var + 1e-5f);
#pragma unroll
    for (int i = 0; i < 4; ++i) {
        const int c = tid + 256 * i;
        xnf[(size_t)row * D_MODEL + c] = (v[i] - mu) * rs * w[c] + b[c];
    }
}

__global__ __launch_bounds__(256) void gemm_bt(
    const float* __restrict__ A, int lda,
    const float* __restrict__ Bw,
    float* __restrict__ C, int ldc,
    int M, int N, int K, int epi,
    const float* __restrict__ bias,
    const float* __restrict__ resid)
{
    __shared__ float As[BK][BM + 1];
    __shared__ float Bs[BK][BN + 1];
    const int tx = threadIdx.x, ty = threadIdx.y;
    const int tid = ty * 16 + tx;
    const int bm = blockIdx.y * BM, bn = blockIdx.x * BN;
    float acc[8][8];
#pragma unroll
    for (int i = 0; i < 8; ++i)
#pragma unroll
        for (int j = 0; j < 8; ++j) acc[i][j] = 0.f;
    for (int k0 = 0; k0 < K; k0 += BK) {
#pragma unroll
        for (int i = tid; i < BM * BK; i += 256) {
            const int m = i / BK, kk = i % BK;
            As[kk][m] = A[(size_t)(bm + m) * lda + (k0 + kk)];
        }
#pragma unroll
        for (int i = tid; i < BN * BK; i += 256) {
            const int n = i / BK, kk = i % BK;
            const int gn = bn + n;
            Bs[kk][n] = (gn < N) ? Bw[(size_t)gn * K + (k0 + kk)] : 0.f;
        }
        __syncthreads();
#pragma unroll
        for (int kk = 0; kk < BK; ++kk) {
            float av[8], bv[8];
#pragma unroll
            for (int i = 0; i < 8; ++i) av[i] = As[kk][ty * 8 + i];
#pragma unroll
            for (int j = 0; j < 8; ++j) bv[j] = Bs[kk][tx * 8 + j];
#pragma unroll
            for (int i = 0; i < 8; ++i)
#pragma unroll
                for (int j = 0; j < 8; ++j) acc[i][j] += av[i] * bv[j];
        }
        __syncthreads();
    }
#pragma unroll
    for (int i = 0; i < 8; ++i) {
        const int gm = bm + ty * 8 + i;
#pragma unroll
        for (int j = 0; j < 8; ++j) {
            const int gn = bn + tx * 8 + j;
            if (gn >= N) continue;
            float v = acc[i][j];
            if (epi == 1) {
                v += bias[gn];
                v = fmaxf(v, 0.f) + log1pf(expf(-fabsf(v)));
            } else if (epi == 2) {
                v += resid[(size_t)gm * ldc + gn];
            }
            C[(size_t)gm * ldc + gn] = v;
        }
    }
}

__global__ __launch_bounds__(256) void conv_silu_kernel(
    float* __restrict__ xz, const float* __restrict__ cw,
    const float* __restrict__ cb)
{
    const int idx = blockIdx.x * 256 + threadIdx.x;
    const int b = idx >> 11, d = idx & (D_INNER - 1);
    const float w0 = cw[d * 4 + 0], w1 = cw[d * 4 + 1];
    const float w2 = cw[d * 4 + 2], w3 = cw[d * 4 + 3];
    const float bias = cb[d];
    float* u = xz + (size_t)b * LL * XZ_LD + d;
    float x0 = 0.f, x1 = 0.f, x2 = 0.f;
    for (int t = 0; t < LL; ++t) {
        const float x3 = u[(size_t)t * XZ_LD];
        const float c = bias + x0 * w0 + x1 * w1 + x2 * w2 + x3 * w3;
        u[(size_t)t * XZ_LD] = c / (1.f + expf(-c));
        x0 = x1; x1 = x2; x2 = x3;
    }
}

__global__ __launch_bounds__(256) void scan_kernel(
    float* __restrict__ xz, const float* __restrict__ dtb,
    const float* __restrict__ dbl,
    const float* __restrict__ A_log, const float* __restrict__ Dw)
{
    const int idx = blockIdx.x * 256 + threadIdx.x;
    const int b = idx >> 11, d = idx & (D_INNER - 1);
    float A[D_STATE], h[D_STATE];
#pragma unroll
    for (int n = 0; n < D_STATE; ++n) {
        A[n] = -expf(A_log[d * D_STATE + n]);
        h[n] = 0.f;
    }
    const float Dd = Dw[d];
    const float* dtp  = dtb + (size_t)b * LL * D_INNER + d;
    float*       up   = xz  + (size_t)b * LL * XZ_LD + d;
    const float* dblp = dbl + (size_t)b * LL * DBL_LD;
    for (int t = 0; t < LL; ++t) {
        const float dtv = dtp[(size_t)t * D_INNER];
        const float uv  = up[(size_t)t * XZ_LD];
        const float zv  = up[(size_t)t * XZ_LD + D_INNER];
        const float* Brow = dblp + (size_t)t * DBL_LD + DT_RANK;
        const float* Crow = Brow + D_STATE;
        const float du = dtv * uv;
        float acc = uv * Dd;
#pragma unroll
        for (int n = 0; n < D_STATE; ++n) {
            const float dA = expf(dtv * A[n]);
            h[n] = dA * h[n] + du * Brow[n];
            acc += h[n] * Crow[n];
        }
        const float sz = zv / (1.f + expf(-zv));
        up[(size_t)t * XZ_LD] = acc * sz;
    }
}

extern "C" void kernel_launch(void* const* d_in, const int* in_sizes, int n_in,
                              void* d_out, int out_size, void* d_ws, size_t ws_size,
                              hipStream_t stream)
{
    const float* x       = (const float*)d_in[0];
    const float* ln_w    = (const float*)d_in[1];
    const float* ln_b    = (const float*)d_in[2];
    const float* W_in    = (const float*)d_in[3];
    const float* conv_w  = (const float*)d_in[4];
    const float* conv_b  = (const float*)d_in[5];
    const float* W_xproj = (const float*)d_in[6];
    const float* W_dt    = (const float*)d_in[7];
    const float* b_dt    = (const float*)d_in[8];
    const float* A_log   = (const float*)d_in[9];
    const float* Dw      = (const float*)d_in[10];
    const float* W_out   = (const float*)d_in[11];
    float* out = (float*)d_out;

    // ws layout identical to R15-R17 (134.8 MiB, each size audited):
    //   dtb_bf [0,        4194304)   bf16 dt 4096x2048
    //   uraw   [4194304, 12582912)   fp32 u  4096x2048
    //   zbf    [12582912, 16777216)  bf16 z  4096x2048
    //   Psum   [16777216, 20971520)  fp32; later G7 slab 0
    //   Hloc   [20971520, 25165824)  fp32; later G7 slab 1
    //   dbl    [25165824, 25559040)  fp32 4096x96
    //   ucy    [25559040, 29753344)  bf16 conv(u) then y
    //   xn_bf  [29753344, 31850496)  bf16 4096x1024
    //   win_bf [31850496, 33947648)  bf16 4096x1024
    //   wx_bf  [33947648, 34078720) | wdt_bf [34078720, 34144256)
    //   wout_bf[34144256, 35192832) | dtr_bf [35192832, 35323904)
    float* wsf     = (float*)d_ws;
    bf16*  dtb_bf  = (bf16*)wsf;
    float* uraw    = wsf + 4194304;
    bf16*  zbf     = (bf16*)(wsf + 12582912);
    float* Psum    = wsf + 16777216;       // G7 slabs are contiguous here
    float* Hloc    = wsf + 20971520;
    float* dbl     = wsf + 25165824;
    bf16*  ucy     = (bf16*)(wsf + 25559040);
    bf16*  xn_bf   = (bf16*)(wsf + 29753344);
    bf16*  win_bf  = (bf16*)(wsf + 31850496);
    bf16*  wx_bf   = (bf16*)(wsf + 33947648);
    bf16*  wdt_bf  = (bf16*)(wsf + 34078720);
    bf16*  wout_bf = (bf16*)(wsf + 34144256);
    bf16*  dtr_bf  = (bf16*)(wsf + 35192832);
    const size_t need_big = (size_t)35323904 * sizeof(float);

    if (ws_size >= need_big) {
        wcvt_kernel<<<WCVT_TOT / 256, 256, 0, stream>>>(
            W_in, W_xproj, W_dt, W_out, win_bf, wx_bf, wdt_bf, wout_bf, dbl);
        ln_kernel_bf<<<BL, 256, 0, stream>>>(x, ln_w, ln_b, xn_bf);
        // G2: [u|z] = xn @ W_in^T; u -> fp32 uraw, z -> bf16 zbf  [EPI=4]
        gemm_t<4><<<dim3(XZ_LD / GTN, BL / GTM, 1), 256, 0, stream>>>(
            xn_bf, D_MODEL, win_bf, D_MODEL, uraw, D_INNER,
            XZ_LD, D_MODEL, nullptr, zbf);
        // conv+SiLU: fp32 u -> bf16 uc
        conv_par3<<<(size_t)BL * D_INNER / 256, 256, 0, stream>>>(
            uraw, conv_w, conv_b, ucy);
        // G4: dbl += uc @ W_xproj^T  (N=96 pad 128, split-K=8)  [EPI=3 atomic]
        gemm_t<3><<<dim3(1, BL / GTM, 8), 256, 0, stream>>>(
            ucy, D_INNER, wx_bf, D_INNER, dbl, DBL_LD,
            DBL_LD, D_INNER / 8, nullptr, nullptr);
        cvt_dtr<<<BL * DT_RANK / 256, 256, 0, stream>>>(dbl, dtr_bf);
        // G5: dt = softplus(dt_r @ W_dt^T + b_dt), bf16 store  [EPI=5]
        gemm_t<5><<<dim3(D_INNER / GTN, BL / GTM, 1), 256, 0, stream>>>(
            dtr_bf, DT_RANK, wdt_bf, DT_RANK, nullptr, D_INNER,
            D_INNER, DT_RANK, b_dt, dtb_bf);
        // chunked scan, NCH=64 (exp-power fast path)
        scan_p1<<<BB * NCH * 8, 256, 0, stream>>>(
            ucy, dtb_bf, dbl, A_log, Psum, Hloc);
        scan_p2<<<BB * D_INNER * D_STATE / 256, 256, 0, stream>>>(Psum, Hloc);
        scan_p3b<<<BB * NCH * 8, 256, 0, stream>>>(
            ucy, dtb_bf, dbl, A_log, Dw, Psum, zbf);
        // G7: partials = y @ W_out^T  (split-K=2 into Psum/Hloc slabs) [EPI=0]
        gemm_t<0><<<dim3(D_MODEL / GTN, BL / GTM, 2), 256, 0, stream>>>(
            ucy, D_INNER, wout_bf, D_INNER, Psum, D_MODEL,
            D_MODEL, D_INNER / 2, nullptr, nullptr);
        // out = x + p0 + p1
        reduce_out<<<BL * D_MODEL / 4 / 256, 256, 0, stream>>>(
            x, Psum, Hloc, out);
    } else {
        float* fdtb = wsf;
        float* fxn  = fdtb;
        float* fxz  = fdtb + (size_t)BL * D_INNER;
        float* fdbl = fxz + (size_t)BL * XZ_LD;
        ln_kernel<<<BL, 256, 0, stream>>>(x, ln_w, ln_b, fxn);
        dim3 blk(16, 16);
        gemm_bt<<<dim3(XZ_LD / BN, BL / BM), blk, 0, stream>>>(
            fxn, D_MODEL, W_in, fxz, XZ_LD, BL, XZ_LD, D_MODEL, 0, nullptr, nullptr);
        conv_silu_kernel<<<(BB * D_INNER) / 256, 256, 0, stream>>>(fxz, conv_w, conv_b);
        gemm_bt<<<dim3(1, BL / BM), blk, 0, stream>>>(
            fxz, XZ_LD, W_xproj, fdbl, DBL_LD, BL, DBL_LD, D_INNER, 0, nullptr, nullptr);
        gemm_bt<<<dim3(D_INNER / BN, BL / BM), blk, 0, stream>>>(
            fdbl, DBL_LD, W_dt, fdtb, D_INNER, BL, D_INNER, DT_RANK, 1, b_dt, nullptr);
        scan_kernel<<<(BB * D_INNER) / 256, 256, 0, stream>>>(fxz, fdtb, fdbl, A_log, Dw);
        gemm_bt<<<dim3(D_MODEL / BN, BL / BM), blk, 0, stream>>>(
            fxz, XZ_LD, W_out, out, D_MODEL, BL, D_MODEL, D_INNER, 2, nullptr, x);
    }
}

// Round 19
// 344.841 us; speedup vs baseline: 1.1435x; 1.0244x over previous
//
#include <hip/hip_runtime.h>
#include <hip/hip_bf16.h>
#include <stdint.h>

typedef __hip_bfloat16 bf16;
typedef __attribute__((ext_vector_type(8))) short short8;
typedef __attribute__((ext_vector_type(4))) float floatx4;

#define D_MODEL 1024
#define D_STATE 16
#define D_INNER 2048
#define DT_RANK 64
#define BB 2
#define LL 2048
#define BL (BB * LL)            // 4096 rows
#define XZ_LD (2 * D_INNER)     // 4096 (fallback path only)
#define DBL_LD (DT_RANK + 2 * D_STATE)  // 96
#define NCH 64                  // time chunks for parallel scan
#define TCH (LL / NCH)          // 32 steps per chunk

__device__ __forceinline__ bf16 f2b(float f) { return __float2bfloat16(f); }

// fast sigmoid / softplus via native v_exp/v_log/v_rcp (~3e-7 rel err)
__device__ __forceinline__ float fsig(float v)  { return __fdividef(1.f, 1.f + __expf(-v)); }
__device__ __forceinline__ float fsoftp(float v){ return fmaxf(v, 0.f) + __logf(1.f + __expf(-fabsf(v))); }

// async 16B global -> LDS (wave-uniform LDS base + lane*16; rows contiguous)
__device__ __forceinline__ void gload16(const void* g, void* l) {
    __builtin_amdgcn_global_load_lds(
        (const __attribute__((address_space(1))) uint32_t*)(uintptr_t)g,
        (__attribute__((address_space(3))) uint32_t*)(uintptr_t)l,
        16, 0, 0);
}

#define S0 (4096 * 1024)   // W_in
#define S1 (128 * 2048)    // W_xproj padded to 128 rows
#define S2 (2048 * 64)     // W_dt
#define S3 (1024 * 2048)   // W_out
#define S4 (BL * DBL_LD)   // dbl zero-init (for split-K atomics)
#define WCVT_TOT (S0 + S1 + S2 + S3 + S4)

// ------- fused prep: LN (blocks 0..BL-1) + weight cvt (+dbl zero) -----------
// R16/R17 proved R15's G2 regression came from the shared GEMM's epilogue
// branches, NOT this fusion — both fused and split orders ran G2 at 99 us
// with the 5-branch binary; specialization fixed it. Fusing saves a launch.
__global__ __launch_bounds__(256) void prep_kernel(
    const float* __restrict__ x, const float* __restrict__ w,
    const float* __restrict__ b, bf16* __restrict__ xnb,
    const float* __restrict__ Win, const float* __restrict__ Wx,
    const float* __restrict__ Wdt, const float* __restrict__ Wout,
    bf16* __restrict__ win_bf, bf16* __restrict__ wx_bf,
    bf16* __restrict__ wdt_bf, bf16* __restrict__ wout_bf,
    float* __restrict__ dbl)
{
    __shared__ float s1[256], s2[256];
    const int tid = threadIdx.x;
    if (blockIdx.x < BL) {
        const int row = blockIdx.x;
        const float* xr = x + (size_t)row * D_MODEL;
        float v[4], sum = 0.f, sq = 0.f;
#pragma unroll
        for (int i = 0; i < 4; ++i) {
            v[i] = xr[tid + 256 * i];
            sum += v[i];
            sq  += v[i] * v[i];
        }
        s1[tid] = sum; s2[tid] = sq;
        __syncthreads();
        for (int s = 128; s > 0; s >>= 1) {
            if (tid < s) { s1[tid] += s1[tid + s]; s2[tid] += s2[tid + s]; }
            __syncthreads();
        }
        const float mu  = s1[0] * (1.f / D_MODEL);
        const float var = s2[0] * (1.f / D_MODEL) - mu * mu;
        const float rs  = rsqrtf(var + 1e-5f);
#pragma unroll
        for (int i = 0; i < 4; ++i) {
            const int c = tid + 256 * i;
            xnb[(size_t)row * D_MODEL + c] = f2b((v[i] - mu) * rs * w[c] + b[c]);
        }
    } else {
        int id = (blockIdx.x - BL) * 256 + tid;
        if (id < S0) { win_bf[id] = f2b(Win[id]); return; }
        id -= S0;
        if (id < S1) { wx_bf[id] = (id < 96 * 2048) ? f2b(Wx[id]) : f2b(0.f); return; }
        id -= S1;
        if (id < S2) { wdt_bf[id] = f2b(Wdt[id]); return; }
        id -= S2;
        if (id < S3) { wout_bf[id] = f2b(Wout[id]); return; }
        id -= S3;
        dbl[id] = 0.f;
    }
}

// ===== bf16 MFMA GEMM, compile-time-specialized epilogues (R17-proven) =======
// EPI: 3=atomicAdd (split-K); 4=u/z split (gn<D_INNER -> fp32 C else bf16 C2);
// 5=softplus bf16 -> C2.   (UNTOUCHED from R18 — G2 at 66.5 us depends on it.)
#define GTM 128
#define GTN 128
#define GTK 32

template <int EPI>
__global__ __launch_bounds__(256) void gemm_t(
    const bf16* __restrict__ A, int lda,
    const bf16* __restrict__ B, int ldb,
    float* __restrict__ C, int ldc,
    int N, int K,
    const float* __restrict__ bias,
    bf16* __restrict__ C2)
{
    __shared__ short As[GTM * GTK];   // 8 KB
    __shared__ short Bs[GTN * GTK];   // 8 KB
    const int tid  = threadIdx.x;
    const int lane = tid & 63;
    const int wave = tid >> 6;            // 0..3
    const int wm = (wave & 1) * 64;
    const int wn = (wave >> 1) * 64;
    const int bm = blockIdx.y * GTM;
    const int bn = blockIdx.x * GTN;
    const int kbase = blockIdx.z * K;     // split-K base (K = slice length)

    floatx4 acc[4][4];
#pragma unroll
    for (int i = 0; i < 4; ++i)
#pragma unroll
        for (int j = 0; j < 4; ++j) acc[i][j] = (floatx4){0.f, 0.f, 0.f, 0.f};

    const int srow = wave * 16 + (lane >> 2);   // 0..63 (per pass)
    const int scol = (lane & 3) * 8;            // bf16 col within k-tile
    const int fm = lane & 15;
    const int q  = lane >> 4;

    for (int k0 = 0; k0 < K; k0 += GTK) {
#pragma unroll
        for (int r = 0; r < 2; ++r) {
            const int m = r * 64 + srow;
            gload16(A + (size_t)(bm + m) * lda + kbase + k0 + scol,
                    As + m * GTK + scol);
            gload16(B + (size_t)(bn + m) * ldb + kbase + k0 + scol,
                    Bs + m * GTK + scol);
        }
        __syncthreads();

        short8 af[4], bfr[4];
#pragma unroll
        for (int i = 0; i < 4; ++i)
            af[i] = *(short8*)&As[(wm + i * 16 + fm) * GTK + q * 8];
#pragma unroll
        for (int j = 0; j < 4; ++j)
            bfr[j] = *(short8*)&Bs[(wn + j * 16 + fm) * GTK + q * 8];
#pragma unroll
        for (int i = 0; i < 4; ++i)
#pragma unroll
            for (int j = 0; j < 4; ++j)
                acc[i][j] = __builtin_amdgcn_mfma_f32_16x16x32_bf16(
                    af[i], bfr[j], acc[i][j], 0, 0, 0);
        __syncthreads();
    }

    // C/D layout: col=lane&15, row=(lane>>4)*4+reg  [m89/m91-verified]
    const int col = lane & 15;
    const int rq  = (lane >> 4) * 4;
#pragma unroll
    for (int i = 0; i < 4; ++i) {
#pragma unroll
        for (int j = 0; j < 4; ++j) {
#pragma unroll
            for (int r = 0; r < 4; ++r) {
                const int gm = bm + wm + i * 16 + rq + r;
                const int gn = bn + wn + j * 16 + col;
                if (gn >= N) continue;
                float v = acc[i][j][r];
                if constexpr (EPI == 3) {
                    atomicAdd(&C[(size_t)gm * ldc + gn], v);
                } else if constexpr (EPI == 4) {
                    if (gn < D_INNER) C[(size_t)gm * ldc + gn] = v;
                    else C2[(size_t)gm * (size_t)D_INNER + (gn - D_INNER)] = f2b(v);
                } else {  // EPI == 5
                    C2[(size_t)gm * ldc + gn] = f2b(fsoftp(v + bias[gn]));
                }
            }
        }
    }
}

// ===== G7-dedicated GEMM: 128x64 tiles, no split-K, out = acc + x ============
// M=4096, N=1024, K=2048 -> grid (16, 32) = 512 blocks (2/CU) with a direct
// residual epilogue: removes the two 16 MB slab writes + 64 MB reduce pass.
#define OTM 128
#define OTN 64

__global__ __launch_bounds__(256) void gemm_out(
    const bf16* __restrict__ A, int lda,
    const bf16* __restrict__ B, int ldb,
    const float* __restrict__ resid,
    float* __restrict__ C)               // ldc = D_MODEL
{
    __shared__ short As[OTM * GTK];   // 8 KB
    __shared__ short Bs[OTN * GTK];   // 4 KB
    const int tid  = threadIdx.x;
    const int lane = tid & 63;
    const int wave = tid >> 6;            // 0..3
    const int wm = (wave & 1) * 64;
    const int wn = (wave >> 1) * 32;
    const int bm = blockIdx.y * OTM;
    const int bn = blockIdx.x * OTN;

    floatx4 acc[4][2];
#pragma unroll
    for (int i = 0; i < 4; ++i)
#pragma unroll
        for (int j = 0; j < 2; ++j) acc[i][j] = (floatx4){0.f, 0.f, 0.f, 0.f};

    const int srow = wave * 16 + (lane >> 2);   // 0..63 (per pass)
    const int scol = (lane & 3) * 8;
    const int fm = lane & 15;
    const int q  = lane >> 4;

    for (int k0 = 0; k0 < D_INNER; k0 += GTK) {
        // pass 0/1: A rows 0-63 / 64-127; pass 2: B rows 0-63
        gload16(A + (size_t)(bm + srow) * lda + k0 + scol,
                As + srow * GTK + scol);
        gload16(A + (size_t)(bm + 64 + srow) * lda + k0 + scol,
                As + (64 + srow) * GTK + scol);
        gload16(B + (size_t)(bn + srow) * ldb + k0 + scol,
                Bs + srow * GTK + scol);
        __syncthreads();

        short8 af[4], bfr[2];
#pragma unroll
        for (int i = 0; i < 4; ++i)
            af[i] = *(short8*)&As[(wm + i * 16 + fm) * GTK + q * 8];
#pragma unroll
        for (int j = 0; j < 2; ++j)
            bfr[j] = *(short8*)&Bs[(wn + j * 16 + fm) * GTK + q * 8];
#pragma unroll
        for (int i = 0; i < 4; ++i)
#pragma unroll
            for (int j = 0; j < 2; ++j)
                acc[i][j] = __builtin_amdgcn_mfma_f32_16x16x32_bf16(
                    af[i], bfr[j], acc[i][j], 0, 0, 0);
        __syncthreads();
    }

    const int col = lane & 15;
    const int rq  = (lane >> 4) * 4;
#pragma unroll
    for (int i = 0; i < 4; ++i) {
#pragma unroll
        for (int j = 0; j < 2; ++j) {
#pragma unroll
            for (int r = 0; r < 4; ++r) {
                const int gm = bm + wm + i * 16 + rq + r;
                const int gn = bn + wn + j * 16 + col;
                C[(size_t)gm * D_MODEL + gn] =
                    acc[i][j][r] + resid[(size_t)gm * D_MODEL + gn];
            }
        }
    }
}

// ------------- conv(4)+SiLU: reads fp32 uraw, writes bf16 uc -----------------
__global__ __launch_bounds__(256) void conv_par3(
    const float* __restrict__ uraw, const float* __restrict__ cw,
    const float* __restrict__ cb, bf16* __restrict__ ucb)
{
    const int id = blockIdx.x * 256 + threadIdx.x;  // = (b*LL+t)*D_INNER+d
    const int d = id & (D_INNER - 1);
    const int t = (id >> 11) & (LL - 1);
    float acc = cb[d];
#pragma unroll
    for (int k = 0; k < 4; ++k) {
        const int tt = t - 3 + k;
        if (tt >= 0)
            acc += uraw[(size_t)id + (size_t)(k - 3) * D_INNER] * cw[d * 4 + k];
    }
    ucb[id] = f2b(acc * fsig(acc));
}

// ------------- dbl[:, :64] -> bf16 dt_r copy for GEMM-5 ----------------------
__global__ __launch_bounds__(256) void cvt_dtr(
    const float* __restrict__ dbl, bf16* __restrict__ dtr_bf)
{
    const int id = blockIdx.x * 256 + threadIdx.x;  // m*64+r
    const int m = id >> 6, r = id & 63;
    dtr_bf[id] = f2b(dbl[(size_t)m * DBL_LD + r]);
}

// ------------------------------ 3-phase scan ---------------------------------
// A[n] = -(n+1) exactly (A_log = log(arange(1..16))) -> exp(dt*A[n]) =
// e1^(n+1), e1 = exp(-dt): 1 exp + 15 muls per t. Verified per-thread; general
// fallback otherwise.  blk = ((b*NCH)+c)*8 + dgrp ; d = dgrp*256 + tid
__global__ __launch_bounds__(256) void scan_p1(
    const bf16* __restrict__ uc, const bf16* __restrict__ dtb,
    const float* __restrict__ dbl, const float* __restrict__ A_log,
    float* __restrict__ Psum, float* __restrict__ Hloc)
{
    const int blk = blockIdx.x;
    const int d = (blk & 7) * 256 + threadIdx.x;
    const int c = (blk >> 3) & (NCH - 1);
    const int b = blk >> 9;                  // NCH=64 -> 9 bits below b
    float A[D_STATE], h[D_STATE];
    bool lin = true;
#pragma unroll
    for (int n = 0; n < D_STATE; ++n) {
        A[n] = -__expf(A_log[d * D_STATE + n]);
        lin = lin && (fabsf(A[n] + (float)(n + 1)) < 1e-3f);
        h[n] = 0.f;
    }
    const size_t row0 = (size_t)b * LL + c * TCH;
    const bf16* dtp = dtb + row0 * D_INNER + d;
    const bf16* up  = uc  + row0 * D_INNER + d;
    const float* Bp = dbl + row0 * DBL_LD + DT_RANK;
    float S = 0.f;
    if (lin) {
        for (int t = 0; t < TCH; ++t) {
            const float dtv = (float)dtp[(size_t)t * D_INNER];
            const float uv  = (float)up[(size_t)t * D_INNER];
            const float du  = dtv * uv;
            S += dtv;
            const float e1 = __expf(-dtv);
            float dA = 1.f;
#pragma unroll
            for (int n = 0; n < D_STATE; ++n) {
                dA *= e1;                       // e1^(n+1)
                h[n] = dA * h[n] + du * Bp[(size_t)t * DBL_LD + n];
            }
        }
    } else {
        for (int t = 0; t < TCH; ++t) {
            const float dtv = (float)dtp[(size_t)t * D_INNER];
            const float uv  = (float)up[(size_t)t * D_INNER];
            const float du  = dtv * uv;
            S += dtv;
#pragma unroll
            for (int n = 0; n < D_STATE; ++n)
                h[n] = __expf(dtv * A[n]) * h[n] + du * Bp[(size_t)t * DBL_LD + n];
        }
    }
    const size_t o = (((size_t)b * NCH + c) * D_INNER + d) * D_STATE;
    if (lin) {
        const float E1 = __expf(-S);
        float P = 1.f;
#pragma unroll
        for (int n = 0; n < D_STATE; ++n) {
            P *= E1;
            Psum[o + n] = P;
            Hloc[o + n] = h[n];
        }
    } else {
#pragma unroll
        for (int n = 0; n < D_STATE; ++n) {
            Psum[o + n] = __expf(S * A[n]);
            Hloc[o + n] = h[n];
        }
    }
}

__global__ __launch_bounds__(256) void scan_p2(
    float* __restrict__ Psum, const float* __restrict__ Hloc)
{
    const int id = blockIdx.x * 256 + threadIdx.x;
    const int dn = id & (D_INNER * D_STATE - 1);
    const int b  = id >> 15;
    float h = 0.f;
    for (int c = 0; c < NCH; ++c) {
        const size_t o = ((size_t)(b * NCH + c) * D_INNER * D_STATE) + dn;
        const float P  = Psum[o];
        const float hl = Hloc[o];
        Psum[o] = h;          // Hin for chunk c
        h = P * h + hl;
    }
}

// phase 3: replay; bf16 u (ucy), bf16 dt, bf16 z (zbf); y overwrites ucy
__global__ __launch_bounds__(256) void scan_p3b(
    bf16* __restrict__ ucy, const bf16* __restrict__ dtb,
    const float* __restrict__ dbl, const float* __restrict__ A_log,
    const float* __restrict__ Dw, const float* __restrict__ Hin,
    const bf16* __restrict__ zbf)
{
    const int blk = blockIdx.x;
    const int d = (blk & 7) * 256 + threadIdx.x;
    const int c = (blk >> 3) & (NCH - 1);
    const int b = blk >> 9;                  // NCH=64 -> 9 bits below b
    float A[D_STATE], h[D_STATE];
    const size_t o = (((size_t)b * NCH + c) * D_INNER + d) * D_STATE;
    bool lin = true;
#pragma unroll
    for (int n = 0; n < D_STATE; ++n) {
        A[n] = -__expf(A_log[d * D_STATE + n]);
        lin = lin && (fabsf(A[n] + (float)(n + 1)) < 1e-3f);
        h[n] = Hin[o + n];
    }
    const float Dd = Dw[d];
    const size_t row0 = (size_t)b * LL + c * TCH;
    const bf16* dtp = dtb + row0 * D_INNER + d;
    bf16*       uyp = ucy + row0 * D_INNER + d;     // u in, y out (same slot)
    const float* BCp = dbl + row0 * DBL_LD;
    const bf16* zp   = zbf + row0 * D_INNER + d;
    if (lin) {
        for (int t = 0; t < TCH; ++t) {
            const float dtv = (float)dtp[(size_t)t * D_INNER];
            const float uv  = (float)uyp[(size_t)t * D_INNER];
            const float du  = dtv * uv;
            float acc = uv * Dd;
            const float* Brow = BCp + (size_t)t * DBL_LD + DT_RANK;
            const float* Crow = Brow + D_STATE;
            const float e1 = __expf(-dtv);
            float dA = 1.f;
#pragma unroll
            for (int n = 0; n < D_STATE; ++n) {
                dA *= e1;                       // e1^(n+1)
                h[n] = dA * h[n] + du * Brow[n];
                acc += h[n] * Crow[n];
            }
            const float zv = (float)zp[(size_t)t * D_INNER];
            uyp[(size_t)t * D_INNER] = f2b(acc * zv * fsig(zv));
        }
    } else {
        for (int t = 0; t < TCH; ++t) {
            const float dtv = (float)dtp[(size_t)t * D_INNER];
            const float uv  = (float)uyp[(size_t)t * D_INNER];
            const float du  = dtv * uv;
            float acc = uv * Dd;
            const float* Brow = BCp + (size_t)t * DBL_LD + DT_RANK;
            const float* Crow = Brow + D_STATE;
#pragma unroll
            for (int n = 0; n < D_STATE; ++n) {
                h[n] = __expf(dtv * A[n]) * h[n] + du * Brow[n];
                acc += h[n] * Crow[n];
            }
            const float zv = (float)zp[(size_t)t * D_INNER];
            uyp[(size_t)t * D_INNER] = f2b(acc * zv * fsig(zv));
        }
    }
}

// ---------------- fallback (small ws): R4 sequential path --------------------
#define BM 128
#define BN 128
#define BK 8

__global__ __launch_bounds__(256) void ln_kernel(
    const float* __restrict__ x, const float* __restrict__ w,
    const float* __restrict__ b, float* __restrict__ xnf)
{
    __shared__ float s1[256], s2[256];
    const int row = blockIdx.x;
    const int tid = threadIdx.x;
    const float* xr = x + (size_t)row * D_MODEL;
    float v[4], sum = 0.f, sq = 0.f;
#pragma unroll
    for (int i = 0; i < 4; ++i) {
        v[i] = xr[tid + 256 * i];
        sum += v[i];
        sq  += v[i] * v[i];
    }
    s1[tid] = sum; s2[tid] = sq;
    __syncthreads();
    for (int s = 128; s > 0; s >>= 1) {
        if (tid < s) { s1[tid] += s1[tid + s]; s2[tid] += s2[tid + s]; }
        __syncthreads();
    }
    const float mu  = s1[0] * (1.f / D_MODEL);
    const float var = s2[0] * (1.f / D_MODEL) - mu * mu;
    const float rs  = rsqrtf(var + 1e-5f);
#pragma unroll
    for (int i = 0; i < 4; ++i) {
        const int c = tid + 256 * i;
        xnf[(size_t)row * D_MODEL + c] = (v[i] - mu) * rs * w[c] + b[c];
    }
}

__global__ __launch_bounds__(256) void gemm_bt(
    const float* __restrict__ A, int lda,
    const float* __restrict__ Bw,
    float* __restrict__ C, int ldc,
    int M, int N, int K, int epi,
    const float* __restrict__ bias,
    const float* __restrict__ resid)
{
    __shared__ float As[BK][BM + 1];
    __shared__ float Bs[BK][BN + 1];
    const int tx = threadIdx.x, ty = threadIdx.y;
    const int tid = ty * 16 + tx;
    const int bm = blockIdx.y * BM, bn = blockIdx.x * BN;
    float acc[8][8];
#pragma unroll
    for (int i = 0; i < 8; ++i)
#pragma unroll
        for (int j = 0; j < 8; ++j) acc[i][j] = 0.f;
    for (int k0 = 0; k0 < K; k0 += BK) {
#pragma unroll
        for (int i = tid; i < BM * BK; i += 256) {
            const int m = i / BK, kk = i % BK;
            As[kk][m] = A[(size_t)(bm + m) * lda + (k0 + kk)];
        }
#pragma unroll
        for (int i = tid; i < BN * BK; i += 256) {
            const int n = i / BK, kk = i % BK;
            const int gn = bn + n;
            Bs[kk][n] = (gn < N) ? Bw[(size_t)gn * K + (k0 + kk)] : 0.f;
        }
        __syncthreads();
#pragma unroll
        for (int kk = 0; kk < BK; ++kk) {
            float av[8], bv[8];
#pragma unroll
            for (int i = 0; i < 8; ++i) av[i] = As[kk][ty * 8 + i];
#pragma unroll
            for (int j = 0; j < 8; ++j) bv[j] = Bs[kk][tx * 8 + j];
#pragma unroll
            for (int i = 0; i < 8; ++i)
#pragma unroll
                for (int j = 0; j < 8; ++j) acc[i][j] += av[i] * bv[j];
        }
        __syncthreads();
    }
#pragma unroll
    for (int i = 0; i < 8; ++i) {
        const int gm = bm + ty * 8 + i;
#pragma unroll
        for (int j = 0; j < 8; ++j) {
            const int gn = bn + tx * 8 + j;
            if (gn >= N) continue;
            float v = acc[i][j];
            if (epi == 1) {
                v += bias[gn];
                v = fmaxf(v, 0.f) + log1pf(expf(-fabsf(v)));
            } else if (epi == 2) {
                v += resid[(size_t)gm * ldc + gn];
            }
            C[(size_t)gm * ldc + gn] = v;
        }
    }
}

__global__ __launch_bounds__(256) void conv_silu_kernel(
    float* __restrict__ xz, const float* __restrict__ cw,
    const float* __restrict__ cb)
{
    const int idx = blockIdx.x * 256 + threadIdx.x;
    const int b = idx >> 11, d = idx & (D_INNER - 1);
    const float w0 = cw[d * 4 + 0], w1 = cw[d * 4 + 1];
    const float w2 = cw[d * 4 + 2], w3 = cw[d * 4 + 3];
    const float bias = cb[d];
    float* u = xz + (size_t)b * LL * XZ_LD + d;
    float x0 = 0.f, x1 = 0.f, x2 = 0.f;
    for (int t = 0; t < LL; ++t) {
        const float x3 = u[(size_t)t * XZ_LD];
        const float c = bias + x0 * w0 + x1 * w1 + x2 * w2 + x3 * w3;
        u[(size_t)t * XZ_LD] = c / (1.f + expf(-c));
        x0 = x1; x1 = x2; x2 = x3;
    }
}

__global__ __launch_bounds__(256) void scan_kernel(
    float* __restrict__ xz, const float* __restrict__ dtb,
    const float* __restrict__ dbl,
    const float* __restrict__ A_log, const float* __restrict__ Dw)
{
    const int idx = blockIdx.x * 256 + threadIdx.x;
    const int b = idx >> 11, d = idx & (D_INNER - 1);
    float A[D_STATE], h[D_STATE];
#pragma unroll
    for (int n = 0; n < D_STATE; ++n) {
        A[n] = -expf(A_log[d * D_STATE + n]);
        h[n] = 0.f;
    }
    const float Dd = Dw[d];
    const float* dtp  = dtb + (size_t)b * LL * D_INNER + d;
    float*       up   = xz  + (size_t)b * LL * XZ_LD + d;
    const float* dblp = dbl + (size_t)b * LL * DBL_LD;
    for (int t = 0; t < LL; ++t) {
        const float dtv = dtp[(size_t)t * D_INNER];
        const float uv  = up[(size_t)t * XZ_LD];
        const float zv  = up[(size_t)t * XZ_LD + D_INNER];
        const float* Brow = dblp + (size_t)t * DBL_LD + DT_RANK;
        const float* Crow = Brow + D_STATE;
        const float du = dtv * uv;
        float acc = uv * Dd;
#pragma unroll
        for (int n = 0; n < D_STATE; ++n) {
            const float dA = expf(dtv * A[n]);
            h[n] = dA * h[n] + du * Brow[n];
            acc += h[n] * Crow[n];
        }
        const float sz = zv / (1.f + expf(-zv));
        up[(size_t)t * XZ_LD] = acc * sz;
    }
}

extern "C" void kernel_launch(void* const* d_in, const int* in_sizes, int n_in,
                              void* d_out, int out_size, void* d_ws, size_t ws_size,
                              hipStream_t stream)
{
    const float* x       = (const float*)d_in[0];
    const float* ln_w    = (const float*)d_in[1];
    const float* ln_b    = (const float*)d_in[2];
    const float* W_in    = (const float*)d_in[3];
    const float* conv_w  = (const float*)d_in[4];
    const float* conv_b  = (const float*)d_in[5];
    const float* W_xproj = (const float*)d_in[6];
    const float* W_dt    = (const float*)d_in[7];
    const float* b_dt    = (const float*)d_in[8];
    const float* A_log   = (const float*)d_in[9];
    const float* Dw      = (const float*)d_in[10];
    const float* W_out   = (const float*)d_in[11];
    float* out = (float*)d_out;

    // ws layout identical to R15-R18 (134.8 MiB, each size audited):
    //   dtb_bf [0,        4194304)   bf16 dt 4096x2048
    //   uraw   [4194304, 12582912)   fp32 u  4096x2048
    //   zbf    [12582912, 16777216)  bf16 z  4096x2048
    //   Psum   [16777216, 20971520)  fp32 scan chunk decay / Hin
    //   Hloc   [20971520, 25165824)  fp32 scan local h
    //   dbl    [25165824, 25559040)  fp32 4096x96
    //   ucy    [25559040, 29753344)  bf16 conv(u) then y
    //   xn_bf  [29753344, 31850496)  bf16 4096x1024
    //   win_bf [31850496, 33947648)  bf16 4096x1024
    //   wx_bf  [33947648, 34078720) | wdt_bf [34078720, 34144256)
    //   wout_bf[34144256, 35192832) | dtr_bf [35192832, 35323904)
    float* wsf     = (float*)d_ws;
    bf16*  dtb_bf  = (bf16*)wsf;
    float* uraw    = wsf + 4194304;
    bf16*  zbf     = (bf16*)(wsf + 12582912);
    float* Psum    = wsf + 16777216;
    float* Hloc    = wsf + 20971520;
    float* dbl     = wsf + 25165824;
    bf16*  ucy     = (bf16*)(wsf + 25559040);
    bf16*  xn_bf   = (bf16*)(wsf + 29753344);
    bf16*  win_bf  = (bf16*)(wsf + 31850496);
    bf16*  wx_bf   = (bf16*)(wsf + 33947648);
    bf16*  wdt_bf  = (bf16*)(wsf + 34078720);
    bf16*  wout_bf = (bf16*)(wsf + 34144256);
    bf16*  dtr_bf  = (bf16*)(wsf + 35192832);
    const size_t need_big = (size_t)35323904 * sizeof(float);

    if (ws_size >= need_big) {
        // fused LN + weight cvt (+dbl zero) — one launch
        prep_kernel<<<BL + WCVT_TOT / 256, 256, 0, stream>>>(
            x, ln_w, ln_b, xn_bf,
            W_in, W_xproj, W_dt, W_out, win_bf, wx_bf, wdt_bf, wout_bf, dbl);
        // G2: [u|z] = xn @ W_in^T; u -> fp32 uraw, z -> bf16 zbf  [EPI=4]
        gemm_t<4><<<dim3(XZ_LD / GTN, BL / GTM, 1), 256, 0, stream>>>(
            xn_bf, D_MODEL, win_bf, D_MODEL, uraw, D_INNER,
            XZ_LD, D_MODEL, nullptr, zbf);
        // conv+SiLU: fp32 u -> bf16 uc
        conv_par3<<<(size_t)BL * D_INNER / 256, 256, 0, stream>>>(
            uraw, conv_w, conv_b, ucy);
        // G4: dbl += uc @ W_xproj^T  (N=96 pad 128, split-K=8)  [EPI=3 atomic]
        gemm_t<3><<<dim3(1, BL / GTM, 8), 256, 0, stream>>>(
            ucy, D_INNER, wx_bf, D_INNER, dbl, DBL_LD,
            DBL_LD, D_INNER / 8, nullptr, nullptr);
        cvt_dtr<<<BL * DT_RANK / 256, 256, 0, stream>>>(dbl, dtr_bf);
        // G5: dt = softplus(dt_r @ W_dt^T + b_dt), bf16 store  [EPI=5]
        gemm_t<5><<<dim3(D_INNER / GTN, BL / GTM, 1), 256, 0, stream>>>(
            dtr_bf, DT_RANK, wdt_bf, DT_RANK, nullptr, D_INNER,
            D_INNER, DT_RANK, b_dt, dtb_bf);
        // chunked scan, NCH=64 (exp-power fast path)
        scan_p1<<<BB * NCH * 8, 256, 0, stream>>>(
            ucy, dtb_bf, dbl, A_log, Psum, Hloc);
        scan_p2<<<BB * D_INNER * D_STATE / 256, 256, 0, stream>>>(Psum, Hloc);
        scan_p3b<<<BB * NCH * 8, 256, 0, stream>>>(
            ucy, dtb_bf, dbl, A_log, Dw, Psum, zbf);
        // G7: out = y @ W_out^T + x  (128x64 tiles, 512 blocks, no split-K)
        gemm_out<<<dim3(D_MODEL / OTN, BL / OTM), 256, 0, stream>>>(
            ucy, D_INNER, wout_bf, D_INNER, x, out);
    } else {
        float* fdtb = wsf;
        float* fxn  = fdtb;
        float* fxz  = fdtb + (size_t)BL * D_INNER;
        float* fdbl = fxz + (size_t)BL * XZ_LD;
        ln_kernel<<<BL, 256, 0, stream>>>(x, ln_w, ln_b, fxn);
        dim3 blk(16, 16);
        gemm_bt<<<dim3(XZ_LD / BN, BL / BM), blk, 0, stream>>>(
            fxn, D_MODEL, W_in, fxz, XZ_LD, BL, XZ_LD, D_MODEL, 0, nullptr, nullptr);
        conv_silu_kernel<<<(BB * D_INNER) / 256, 256, 0, stream>>>(fxz, conv_w, conv_b);
        gemm_bt<<<dim3(1, BL / BM), blk, 0, stream>>>(
            fxz, XZ_LD, W_xproj, fdbl, DBL_LD, BL, DBL_LD, D_INNER, 0, nullptr, nullptr);
        gemm_bt<<<dim3(D_INNER / BN, BL / BM), blk, 0, stream>>>(
            fdbl, DBL_LD, W_dt, fdtb, D_INNER, BL, D_INNER, DT_RANK, 1, b_dt, nullptr);
        scan_kernel<<<(BB * D_INNER) / 256, 256, 0, stream>>>(fxz, fdtb, fdbl, A_log, Dw);
        gemm_bt<<<dim3(D_MODEL / BN, BL / BM), blk, 0, stream>>>(
            fxz, XZ_LD, W_out, out, D_MODEL, BL, D_MODEL, D_INNER, 2, nullptr, x);
    }
}